// Round 10
// baseline (1330.524 us; speedup 1.0000x reference)
//
#include <hip/hip_runtime.h>
#include <hip/hip_bf16.h>

typedef float f32x4 __attribute__((ext_vector_type(4)));
typedef __bf16 bf16x8 __attribute__((ext_vector_type(8)));
typedef unsigned short u16;

#define T_TOK 4096
#define DIMK 2048
#define INTERN 1024
#define NEXP 32
#define NTOPK 6
#define NGRP 8
#define NTOPG 4
#define SINTER 2048
#define MAXPADROWS 29184

__device__ __forceinline__ void glds16(const void* g, void* l) {
    auto* gp = (const __attribute__((address_space(1))) int*)(g);
    auto* lp = (__attribute__((address_space(3))) int*)(l);
    __builtin_amdgcn_global_load_lds(gp, lp, 16, 0, 0);
}

// Chunked+swizzled layout for [Rows][K] bf16: row-chunks 128, k-chunks 64.
// In-chunk (16KB): off = row*64 + ((g ^ (row&7))<<3) + (k&7), g=(k>>3)&7.
__device__ __forceinline__ size_t toff(int row, int k, int K) {
    int g = (k >> 3) & 7;
    return (size_t)(row >> 7) * (size_t)(128 * K) + (size_t)(k >> 6) * 8192 +
           (size_t)((row & 127) * 64 + ((g ^ (row & 7)) << 3) + (k & 7));
}

// ---------------- cast x fp32 -> bf16 chunked ----------------
__global__ __launch_bounds__(256) void cast_x_tiled_kernel(const float* __restrict__ in, u16* __restrict__ out) {
    int gi = (blockIdx.x * 256 + threadIdx.x) * 8;
    int row = gi >> 11, k = gi & 2047;
    const float4* p = reinterpret_cast<const float4*>(in + gi);
    float4 a = p[0], b = p[1];
    bf16x8 v;
    v[0] = (__bf16)a.x; v[1] = (__bf16)a.y; v[2] = (__bf16)a.z; v[3] = (__bf16)a.w;
    v[4] = (__bf16)b.x; v[5] = (__bf16)b.y; v[6] = (__bf16)b.z; v[7] = (__bf16)b.w;
    *reinterpret_cast<bf16x8*>(out + toff(row, k, DIMK)) = v;
}

// ---------------- single transpose: fp32 [KD][JD] -> bf16 chunked [JD][KD] ----------------
template <int KD, int JD>
__global__ __launch_bounds__(256) void trans_tiled_kernel(const float* __restrict__ in, u16* __restrict__ out) {
    __shared__ float tile[64 * 65];
    const int t = threadIdx.x;
    const float* ib = in + (size_t)blockIdx.z * KD * JD;
    u16* ob = out + (size_t)blockIdx.z * KD * JD;
    const int j0 = blockIdx.x * 64, k0 = blockIdx.y * 64;
    {
        const int c4 = (t & 15) * 4;
#pragma unroll
        for (int i = 0; i < 4; ++i) {
            const int r = (t >> 4) + i * 16;
            float4 v = *reinterpret_cast<const float4*>(&ib[(size_t)(k0 + r) * JD + j0 + c4]);
            tile[r * 65 + c4 + 0] = v.x;
            tile[r * 65 + c4 + 1] = v.y;
            tile[r * 65 + c4 + 2] = v.z;
            tile[r * 65 + c4 + 3] = v.w;
        }
    }
    __syncthreads();
    {
        const int jl = t >> 2, kh = (t & 3) * 16;
        const int n = j0 + jl;
        bf16x8 v0, v1;
#pragma unroll
        for (int j = 0; j < 8; ++j) v0[j] = (__bf16)tile[(kh + j) * 65 + jl];
#pragma unroll
        for (int j = 0; j < 8; ++j) v1[j] = (__bf16)tile[(kh + 8 + j) * 65 + jl];
        *reinterpret_cast<bf16x8*>(ob + toff(n, k0 + kh, KD)) = v0;
        *reinterpret_cast<bf16x8*>(ob + toff(n, k0 + kh + 8, KD)) = v1;
    }
}

// ---------------- cat transpose: wg,wu [KD][JD] -> Wcat chunked [2*JD][KD] ----------------
template <int KD, int JD>
__global__ __launch_bounds__(256) void cat_trans_kernel(const float* __restrict__ g0, const float* __restrict__ u0,
                                                        u16* __restrict__ out) {
    __shared__ float tile[64 * 65];
    const int t = threadIdx.x;
    const size_t so = (size_t)blockIdx.z * KD * JD;
    u16* ob = out + (size_t)blockIdx.z * (2 * (size_t)KD * JD);
    const int j0 = blockIdx.x * 32, k0 = blockIdx.y * 64;
    const int kl = t >> 2, jf = (t & 3) * 4;
#pragma unroll
    for (int s = 0; s < 2; ++s) {
        const float* src = (s ? u0 : g0) + so;
#pragma unroll
        for (int rep = 0; rep < 2; ++rep) {
            int jb = jf + rep * 16;
            float4 v = *reinterpret_cast<const float4*>(&src[(size_t)(k0 + kl) * JD + j0 + jb]);
            int nl = ((jb >> 4) << 5) + s * 16 + (jb & 15);
            tile[kl * 65 + nl + 0] = v.x;
            tile[kl * 65 + nl + 1] = v.y;
            tile[kl * 65 + nl + 2] = v.z;
            tile[kl * 65 + nl + 3] = v.w;
        }
    }
    __syncthreads();
    {
        const int nl = t >> 2, kh = (t & 3) * 16;
        const int n = 2 * j0 + nl;
        bf16x8 v0, v1;
#pragma unroll
        for (int j = 0; j < 8; ++j) v0[j] = (__bf16)tile[(kh + j) * 65 + nl];
#pragma unroll
        for (int j = 0; j < 8; ++j) v1[j] = (__bf16)tile[(kh + 8 + j) * 65 + nl];
        *reinterpret_cast<bf16x8*>(ob + toff(n, k0 + kh, KD)) = v0;
        *reinterpret_cast<bf16x8*>(ob + toff(n, k0 + kh + 8, KD)) = v1;
    }
}

// ---------------- gate ----------------
__global__ __launch_bounds__(64) void gate_kernel(const float* __restrict__ x, const float* __restrict__ gw,
                                                  int* __restrict__ counts, int* __restrict__ ids,
                                                  int* __restrict__ tok2row, float* __restrict__ wtok) {
    const int t = blockIdx.x;
    const int lane = threadIdx.x;
    __shared__ float logits[NEXP];
    const float4* xr = reinterpret_cast<const float4*>(x + (size_t)t * DIMK);
    for (int e = 0; e < NEXP; ++e) {
        const float4* gr = reinterpret_cast<const float4*>(gw + (size_t)e * DIMK);
        float acc = 0.f;
#pragma unroll
        for (int i = 0; i < DIMK / 4 / 64; ++i) {
            float4 xv = xr[lane + i * 64];
            float4 gv = gr[lane + i * 64];
            acc += xv.x * gv.x + xv.y * gv.y + xv.z * gv.z + xv.w * gv.w;
        }
#pragma unroll
        for (int s = 32; s; s >>= 1) acc += __shfl_xor(acc, s);
        if (lane == 0) logits[e] = acc;
    }
    if (lane != 0) return;
    float sc[NEXP];
#pragma unroll
    for (int e = 0; e < NEXP; ++e) sc[e] = logits[e];
    float mx = sc[0];
#pragma unroll
    for (int e = 1; e < NEXP; ++e) mx = fmaxf(mx, sc[e]);
    float ssum = 0.f;
#pragma unroll
    for (int e = 0; e < NEXP; ++e) { sc[e] = __expf(sc[e] - mx); ssum += sc[e]; }
    const float inv = 1.f / ssum;
    float gsc[NGRP];
#pragma unroll
    for (int g = 0; g < NGRP; ++g) {
        float m2 = sc[g * 4];
#pragma unroll
        for (int j = 1; j < 4; ++j) m2 = fmaxf(m2, sc[g * 4 + j]);
        gsc[g] = m2;
    }
    int gsel = 0;
    for (int r = 0; r < NTOPG; ++r) {
        float bv = -1.f; int bi = 0;
#pragma unroll
        for (int g = 0; g < NGRP; ++g) {
            bool c = (((gsel >> g) & 1) == 0) && (gsc[g] > bv);
            bv = c ? gsc[g] : bv; bi = c ? g : bi;
        }
        gsel |= (1 << bi);
    }
    float msk[NEXP];
#pragma unroll
    for (int e = 0; e < NEXP; ++e) msk[e] = ((gsel >> (e >> 2)) & 1) ? sc[e] : -1.f;
    for (int r = 0; r < NTOPK; ++r) {
        float bv = -3.f; int bi = 0;
#pragma unroll
        for (int e = 0; e < NEXP; ++e) {
            bool c = msk[e] > bv;
            bv = c ? msk[e] : bv; bi = c ? e : bi;
        }
#pragma unroll
        for (int e = 0; e < NEXP; ++e) if (e == bi) msk[e] = -2.f;
        float w = bv * inv;
        int slot = atomicAdd(&counts[bi], 1);
        ids[bi * T_TOK + slot] = t;
        tok2row[t * NTOPK + r] = (bi << 12) | slot;
        wtok[t * NTOPK + r] = w;
    }
}

__global__ void scan_kernel(const int* __restrict__ counts, int* __restrict__ poff) {
    if (threadIdx.x == 0) {
        int o = 0;
        for (int e = 0; e < NEXP; ++e) { poff[e] = o; o += (counts[e] + 127) & ~127; }
    }
}

// ---------------- gather: x fp32 rows -> per-expert padded chunked bf16 A ----------------
__global__ __launch_bounds__(256) void gather_a_kernel(const float* __restrict__ x, const int* __restrict__ ids,
                                                       const int* __restrict__ counts, const int* __restrict__ poff,
                                                       u16* __restrict__ At) {
    const int e = blockIdx.y, bm = blockIdx.x;
    const int M = counts[e];
    if (bm * 128 >= M) return;
    const int t = threadIdx.x;
    const int r = t >> 1, h = t & 1;
    const int lr = bm * 128 + r;
    const int cr = lr < M ? lr : M - 1;
    const int tok = ids[e * T_TOK + cr];
    const float* src = x + (size_t)tok * DIMK;
    u16* dst = At + ((size_t)poff[e] + (size_t)bm * 128) * DIMK + r * 64;
    const int rx = r & 7;
#pragma unroll 2
    for (int kc = 0; kc < DIMK / 64; ++kc) {
#pragma unroll
        for (int gi = 0; gi < 4; ++gi) {
            int g = h * 4 + gi;
            const float* s = src + kc * 64 + g * 8;
            float4 f0 = *reinterpret_cast<const float4*>(s);
            float4 f1 = *reinterpret_cast<const float4*>(s + 4);
            bf16x8 v;
            v[0] = (__bf16)f0.x; v[1] = (__bf16)f0.y; v[2] = (__bf16)f0.z; v[3] = (__bf16)f0.w;
            v[4] = (__bf16)f1.x; v[5] = (__bf16)f1.y; v[6] = (__bf16)f1.z; v[7] = (__bf16)f1.w;
            *reinterpret_cast<bf16x8*>(dst + (size_t)kc * 8192 + ((g ^ rx) << 3)) = v;
        }
    }
}

// ================= 256x128 / BK=64 / 8-wave (4Mx2N) / 3-buf ring / m201-style phases =================
// Per K-tile (iter): ph1 {dsrA(8)+dsrB(4), stage A(kt+2), bar, lgkm0, 16 MFMA, bar}
//                    ph2 {dsrB(4), stage B(kt+2), vmcnt(6|0), bar, lgkm0, 16 MFMA, bar}
// Stage distance 2 iters; steady vmcnt(6) keeps kt+2's 6 loads in flight.
#define GEMM_CORE(NKT, EPILOG)                                                                      \
    const int tid = threadIdx.x, lane = tid & 63, wv = tid >> 6;                                    \
    const int wr = wv >> 1, wc = wv & 1;                                                            \
    const int l15 = lane & 15, lk = lane >> 4;                                                      \
    const int t8 = tid * 8;                                                                         \
    f32x4 acc[4][4];                                                                                \
    _Pragma("unroll") for (int m = 0; m < 4; ++m)                                                   \
        _Pragma("unroll") for (int n = 0; n < 4; ++n) acc[m][n] = {0.f, 0.f, 0.f, 0.f};             \
    auto STGA = [&](int kt, int buf) {                                                              \
        glds16(aCh0 + (size_t)kt * 8192 + t8, &Alds[buf * 16384 + t8]);                             \
        glds16(aCh0 + (size_t)kt * 8192 + 4096 + t8, &Alds[buf * 16384 + 4096 + t8]);               \
        glds16(aCh1 + (size_t)kt * 8192 + t8, &Alds[buf * 16384 + 8192 + t8]);                      \
        glds16(aCh1 + (size_t)kt * 8192 + 12288 + t8 - 8192, &Alds[buf * 16384 + 12288 + t8]);      \
    };                                                                                              \
    auto STGB = [&](int kt, int buf) {                                                              \
        glds16(bCh + (size_t)kt * 8192 + t8, &Blds[buf * 8192 + t8]);                               \
        glds16(bCh + (size_t)kt * 8192 + 4096 + t8, &Blds[buf * 8192 + 4096 + t8]);                 \
    };                                                                                              \
    bf16x8 afr[4][2], bfr[2][2];                                                                    \
    auto DSRA = [&](int buf) {                                                                      \
        _Pragma("unroll") for (int mi = 0; mi < 4; ++mi)                                            \
            _Pragma("unroll") for (int ki = 0; ki < 2; ++ki) {                                      \
                int rl = wr * 64 + mi * 16 + l15;                                                   \
                int g = ki * 4 + lk;                                                                \
                afr[mi][ki] = *reinterpret_cast<const bf16x8*>(                                     \
                    &Alds[buf * 16384 + (rl >> 7) * 8192 + (rl & 127) * 64 + ((g ^ (rl & 7)) << 3)]); \
            }                                                                                       \
    };                                                                                              \
    auto DSRB = [&](int buf, int nh) {                                                              \
        _Pragma("unroll") for (int nj = 0; nj < 2; ++nj)                                            \
            _Pragma("unroll") for (int ki = 0; ki < 2; ++ki) {                                      \
                int rc = wc * 64 + (nh * 2 + nj) * 16 + l15;                                        \
                int g = ki * 4 + lk;                                                                \
                bfr[nj][ki] = *reinterpret_cast<const bf16x8*>(                                     \
                    &Blds[buf * 8192 + rc * 64 + ((g ^ (rc & 7)) << 3)]);                           \
            }                                                                                       \
    };                                                                                              \
    STGA(0, 0); STGB(0, 0);                                                                         \
    STGA(1, 1); STGB(1, 1);                                                                         \
    asm volatile("s_waitcnt vmcnt(6)" ::: "memory");                                                \
    __builtin_amdgcn_s_barrier();                                                                   \
    _Pragma("unroll 1") for (int i = 0; i < NKT; ++i) {                                             \
        const int buf = i % 3, sbuf = (i + 2) % 3;                                                  \
        /* phase 1 */                                                                               \
        DSRA(buf); DSRB(buf, 0);                                                                    \
        if (i + 2 < NKT) STGA(i + 2, sbuf);                                                         \
        __builtin_amdgcn_s_barrier();                                                               \
        asm volatile("s_waitcnt lgkmcnt(0)" ::: "memory");                                          \
        __builtin_amdgcn_sched_barrier(0);                                                          \
        __builtin_amdgcn_s_setprio(1);                                                              \
        _Pragma("unroll") for (int ki = 0; ki < 2; ++ki)                                            \
            _Pragma("unroll") for (int mi = 0; mi < 4; ++mi)                                        \
                _Pragma("unroll") for (int nj = 0; nj < 2; ++nj)                                    \
                    acc[mi][nj] = __builtin_amdgcn_mfma_f32_16x16x32_bf16(afr[mi][ki], bfr[nj][ki], acc[mi][nj], 0, 0, 0); \
        __builtin_amdgcn_s_setprio(0);                                                              \
        __builtin_amdgcn_sched_barrier(0);                                                          \
        __builtin_amdgcn_s_barrier();                                                               \
        /* phase 2 */                                                                               \
        DSRB(buf, 1);                                                                               \
        if (i + 2 < NKT) STGB(i + 2, sbuf);                                                         \
        if (i + 2 < NKT) { asm volatile("s_waitcnt vmcnt(6)" ::: "memory"); }                       \
        else { asm volatile("s_waitcnt vmcnt(0)" ::: "memory"); }                                   \
        __builtin_amdgcn_s_barrier();                                                               \
        asm volatile("s_waitcnt lgkmcnt(0)" ::: "memory");                                          \
        __builtin_amdgcn_sched_barrier(0);                                                          \
        __builtin_amdgcn_s_setprio(1);                                                              \
        _Pragma("unroll") for (int ki = 0; ki < 2; ++ki)                                            \
            _Pragma("unroll") for (int mi = 0; mi < 4; ++mi)                                        \
                _Pragma("unroll") for (int nj = 0; nj < 2; ++nj)                                    \
                    acc[mi][2 + nj] = __builtin_amdgcn_mfma_f32_16x16x32_bf16(afr[mi][ki], bfr[nj][ki], acc[mi][2 + nj], 0, 0, 0); \
        __builtin_amdgcn_s_setprio(0);                                                              \
        __builtin_amdgcn_sched_barrier(0);                                                          \
        __builtin_amdgcn_s_barrier();                                                               \
    }                                                                                               \
    EPILOG

// GEMM1 fused: expert (z<32) + shared (z>=32). H = silu(g)*u with 16-col interleaved Wcat.
__global__ __launch_bounds__(512, 2) void gemm1_fused_kernel(
    const u16* __restrict__ At, const u16* __restrict__ WcatE, u16* __restrict__ H,
    const u16* __restrict__ xbT, const u16* __restrict__ WcatS, u16* __restrict__ Hs,
    const int* __restrict__ counts, const int* __restrict__ poff) {
    __shared__ u16 Alds[3 * 16384];
    __shared__ u16 Blds[3 * 8192];
    constexpr int NKT = DIMK / 64;

    int bm, bn, Mpad, hbase, NNh;
    const u16 *a0, *b0;
    u16* ho;
    if (blockIdx.z < 32) {
        int lin = blockIdx.x + 16 * (blockIdx.y + 16 * blockIdx.z);
        int e = 31 - (((lin >> 11) << 3) | (lin & 7));
        int j = (lin >> 3) & 255;
        bm = j & 15; bn = j >> 4;
        int M = counts[e];
        if (bm * 256 >= M) return;
        Mpad = (M + 127) & ~127;
        hbase = poff[e];
        a0 = At + (size_t)poff[e] * DIMK;
        b0 = WcatE + (size_t)e * 2048 * DIMK;
        ho = H; NNh = 1024;
    } else {
        int lin = blockIdx.x + 16 * (blockIdx.y + 16 * (blockIdx.z - 32));
        int swz = (lin & 7) * 64 + (lin >> 3);
        bm = swz & 15; bn = swz >> 4;
        Mpad = T_TOK; hbase = 0;
        a0 = xbT; b0 = WcatS; ho = Hs; NNh = 2048;
    }
    const u16* aCh0 = a0 + (size_t)(2 * bm + 0) * (128 * DIMK);
    const u16* aCh1 = a0 + (size_t)(2 * bm + 1) * (128 * DIMK);
    const u16* bCh = b0 + (size_t)bn * (128 * DIMK);

    GEMM_CORE(NKT,
        /* epilogue: silu(gate)*up -> H chunked */
        _Pragma("unroll") for (int mi = 0; mi < 4; ++mi) {
            _Pragma("unroll") for (int r = 0; r < 4; ++r) {
                int grow = bm * 256 + wr * 64 + mi * 16 + lk * 4 + r;
                if (grow < Mpad) {
                    _Pragma("unroll") for (int nh = 0; nh < 2; ++nh) {
                        float gg = acc[mi][nh * 2 + 0][r];
                        float uu = acc[mi][nh * 2 + 1][r];
                        float h = gg / (1.f + __expf(-gg)) * uu;
                        int n = bn * 128 + wc * 64 + (nh * 2) * 16 + l15;
                        int jcol = ((n >> 5) << 4) + (n & 15);
                        __bf16 hb = (__bf16)h;
                        ho[toff(hbase + grow, jcol, NNh)] = __builtin_bit_cast(u16, hb);
                    }
                }
            }
        }
    )
}

// GEMM2 fused: expert (z<32) writes Ye rows; shared (z>=32) K-split writes Yss slices.
__global__ __launch_bounds__(512, 2) void gemm2_fused_kernel(
    const u16* __restrict__ H, const u16* __restrict__ wdT, u16* __restrict__ Ye,
    const u16* __restrict__ Hs, const u16* __restrict__ swdT, u16* __restrict__ Yss,
    const int* __restrict__ counts, const int* __restrict__ poff) {
    __shared__ u16 Alds[3 * 16384];
    __shared__ u16 Blds[3 * 8192];
    constexpr int NKT = 16;

    int bm, bn, rowbase, Mlim, AKK, BKK, kt0;
    const u16 *a0, *b0;
    u16* yo;
    if (blockIdx.z < 32) {
        int lin = blockIdx.x + 16 * (blockIdx.y + 16 * blockIdx.z);
        int e = 31 - (((lin >> 11) << 3) | (lin & 7));
        int j = (lin >> 3) & 255;
        bm = j & 15; bn = j >> 4;
        int M = counts[e];
        if (bm * 256 >= M) return;
        Mlim = M; rowbase = poff[e];
        a0 = H + (size_t)poff[e] * INTERN;
        b0 = wdT + (size_t)e * 2048 * INTERN;
        yo = Ye; AKK = INTERN; BKK = INTERN; kt0 = 0;
    } else {
        int lin = blockIdx.x + 16 * (blockIdx.y + 16 * (blockIdx.z - 32));
        int swz = (lin & 7) * 64 + (lin >> 3);
        bm = swz & 15; bn = (swz >> 4) & 15;
        int ks = swz >> 8;
        Mlim = T_TOK; rowbase = ks * T_TOK;
        a0 = Hs; b0 = swdT; yo = Yss;
        AKK = SINTER; BKK = SINTER; kt0 = ks * 16;
    }
    const u16* aCh0 = a0 + (size_t)(2 * bm + 0) * (128 * AKK) + (size_t)kt0 * 8192;
    const u16* aCh1 = a0 + (size_t)(2 * bm + 1) * (128 * AKK) + (size_t)kt0 * 8192;
    const u16* bCh = b0 + (size_t)bn * (128 * BKK) + (size_t)kt0 * 8192;

    GEMM_CORE(NKT,
        _Pragma("unroll") for (int mi = 0; mi < 4; ++mi) {
            _Pragma("unroll") for (int r = 0; r < 4; ++r) {
                int grow = bm * 256 + wr * 64 + mi * 16 + lk * 4 + r;
                if (grow < Mlim) {
                    u16* yr = yo + (size_t)(rowbase + grow) * 2048;
                    _Pragma("unroll") for (int ni = 0; ni < 4; ++ni) {
                        int col = bn * 128 + wc * 64 + ni * 16 + l15;
                        __bf16 yb = (__bf16)acc[mi][ni][r];
                        yr[col] = __builtin_bit_cast(u16, yb);
                    }
                }
            }
        }
    )
}

// ---------------- combine: out[t] = Yss0[t] + Yss1[t] + sum_r w_r * Ye[row_r] ----------------
__global__ __launch_bounds__(256) void combine_kernel(const u16* __restrict__ Yss, const u16* __restrict__ Ye,
                                                      const int* __restrict__ tok2row, const float* __restrict__ wtok,
                                                      const int* __restrict__ poff, float* __restrict__ out) {
    const int t = blockIdx.x;
    const int c = threadIdx.x * 8;
    bf16x8 v0 = *reinterpret_cast<const bf16x8*>(Yss + (size_t)t * 2048 + c);
    bf16x8 v1 = *reinterpret_cast<const bf16x8*>(Yss + (size_t)(T_TOK + t) * 2048 + c);
    float acc[8];
#pragma unroll
    for (int j = 0; j < 8; ++j) acc[j] = (float)v0[j] + (float)v1[j];
#pragma unroll
    for (int r = 0; r < NTOPK; ++r) {
        int pk = tok2row[t * NTOPK + r];
        int e = pk >> 12, sl = pk & 4095;
        int row = poff[e] + sl;
        float w = wtok[t * NTOPK + r];
        bf16x8 v = *reinterpret_cast<const bf16x8*>(Ye + (size_t)row * 2048 + c);
#pragma unroll
        for (int j = 0; j < 8; ++j) acc[j] += w * (float)v[j];
    }
    float4 o0 = {acc[0], acc[1], acc[2], acc[3]};
    float4 o1 = {acc[4], acc[5], acc[6], acc[7]};
    float4* po = reinterpret_cast<float4*>(out + (size_t)t * 2048 + c);
    po[0] = o0; po[1] = o1;
}

extern "C" void kernel_launch(void* const* d_in, const int* in_sizes, int n_in,
                              void* d_out, int out_size, void* d_ws, size_t ws_size,
                              hipStream_t stream) {
    const float* x = (const float*)d_in[0];
    const float* gate_w = (const float*)d_in[1];
    const float* wg = (const float*)d_in[2];
    const float* wu = (const float*)d_in[3];
    const float* wd = (const float*)d_in[4];
    const float* swg = (const float*)d_in[5];
    const float* swu = (const float*)d_in[6];
    const float* swd = (const float*)d_in[7];
    float* out = (float*)d_out;

    char* ws = (char*)d_ws;
    size_t off = 0;
    auto alloc = [&](size_t bytes) {
        void* p = ws + off;
        off = (off + bytes + 255) & ~(size_t)255;
        return p;
    };
    u16* xbT = (u16*)alloc((size_t)T_TOK * DIMK * 2);                  // 16.8 MB
    u16* At = (u16*)alloc((size_t)MAXPADROWS * DIMK * 2);              // 119.6 MB
    u16* H = (u16*)alloc((size_t)MAXPADROWS * INTERN * 2);             // 59.8 MB
    u16* Hs = (u16*)alloc((size_t)T_TOK * SINTER * 2);                 // 16.8 MB
    u16* Yss = (u16*)alloc((size_t)2 * T_TOK * 2048 * 2);              // 33.6 MB
    int* ids = (int*)alloc((size_t)NEXP * T_TOK * 4);
    int* tok2row = (int*)alloc((size_t)T_TOK * NTOPK * 4);
    float* wtok = (float*)alloc((size_t)T_TOK * NTOPK * 4);
    int* counts = (int*)alloc(NEXP * 4);
    int* poff = (int*)alloc(NEXP * 4);
    u16* WcatS = (u16*)alloc((size_t)(2 * SINTER) * DIMK * 2);         // 16.8 MB
    u16* swdT = (u16*)alloc((size_t)DIMK * SINTER * 2);                // 8.4 MB
    u16* WcatE = (u16*)alloc((size_t)NEXP * (2 * INTERN) * DIMK * 2);  // 268.4 MB
    u16* wdT = WcatE;  // alias: wd transpose runs after fused GEMM1 consumed WcatE
    u16* Ye = At;      // alias: Ye written by GEMM2 after At is dead (GEMM1 done)

    hipMemsetAsync(counts, 0, NEXP * 4, stream);
    cast_x_tiled_kernel<<<(T_TOK * DIMK) / (256 * 8), 256, 0, stream>>>(x, xbT);
    gate_kernel<<<T_TOK, 64, 0, stream>>>(x, gate_w, counts, ids, tok2row, wtok);
    scan_kernel<<<1, 64, 0, stream>>>(counts, poff);
    gather_a_kernel<<<dim3(32, NEXP), 256, 0, stream>>>(x, ids, counts, poff, At);

    // weight reshapes
    cat_trans_kernel<DIMK, SINTER><<<dim3(SINTER / 32, DIMK / 64, 1), 256, 0, stream>>>(swg, swu, WcatS);
    cat_trans_kernel<DIMK, INTERN><<<dim3(INTERN / 32, DIMK / 64, NEXP), 256, 0, stream>>>(wg, wu, WcatE);
    trans_tiled_kernel<SINTER, DIMK><<<dim3(DIMK / 64, SINTER / 64, 1), 256, 0, stream>>>(swd, swdT);

    // fused GEMM1: expert (z<32) + shared (z in {32,33})
    gemm1_fused_kernel<<<dim3(16, 16, 34), 512, 0, stream>>>(
        At, WcatE, H, xbT, WcatS, Hs, counts, poff);

    // wd transpose into aliased WcatE region (GEMM1 done by stream order)
    trans_tiled_kernel<INTERN, DIMK><<<dim3(DIMK / 64, INTERN / 64, NEXP), 256, 0, stream>>>(wd, wdT);

    // fused GEMM2: expert (z<32) + shared K-split (z in {32,33})
    gemm2_fused_kernel<<<dim3(16, 16, 34), 512, 0, stream>>>(
        H, wdT, Ye, Hs, swdT, Yss, counts, poff);

    // final combine -> out
    combine_kernel<<<T_TOK, 256, 0, stream>>>(Yss, Ye, tok2row, wtok, poff, out);
}

// Round 11
// 1137.124 us; speedup vs baseline: 1.1701x; 1.1701x over previous
//
#include <hip/hip_runtime.h>
#include <hip/hip_bf16.h>

typedef float f32x4 __attribute__((ext_vector_type(4)));
typedef __bf16 bf16x8 __attribute__((ext_vector_type(8)));
typedef unsigned short u16;

#define T_TOK 4096
#define DIMK 2048
#define INTERN 1024
#define NEXP 32
#define NTOPK 6
#define NGRP 8
#define NTOPG 4
#define SINTER 2048
#define MAXPADROWS 29184

__device__ __forceinline__ void glds16(const void* g, void* l) {
    auto* gp = (const __attribute__((address_space(1))) int*)(g);
    auto* lp = (__attribute__((address_space(3))) int*)(l);
    __builtin_amdgcn_global_load_lds(gp, lp, 16, 0, 0);
}

// Chunked+swizzled layout for [Rows][K] bf16: row-chunks 128, k-chunks 64.
// In-chunk (16KB): off = row*64 + ((g ^ (row&7))<<3) + (k&7), g=(k>>3)&7.
__device__ __forceinline__ size_t toff(int row, int k, int K) {
    int g = (k >> 3) & 7;
    return (size_t)(row >> 7) * (size_t)(128 * K) + (size_t)(k >> 6) * 8192 +
           (size_t)((row & 127) * 64 + ((g ^ (row & 7)) << 3) + (k & 7));
}

// ---------------- cast x fp32 -> bf16 chunked ----------------
__global__ __launch_bounds__(256) void cast_x_tiled_kernel(const float* __restrict__ in, u16* __restrict__ out) {
    int gi = (blockIdx.x * 256 + threadIdx.x) * 8;
    int row = gi >> 11, k = gi & 2047;
    const float4* p = reinterpret_cast<const float4*>(in + gi);
    float4 a = p[0], b = p[1];
    bf16x8 v;
    v[0] = (__bf16)a.x; v[1] = (__bf16)a.y; v[2] = (__bf16)a.z; v[3] = (__bf16)a.w;
    v[4] = (__bf16)b.x; v[5] = (__bf16)b.y; v[6] = (__bf16)b.z; v[7] = (__bf16)b.w;
    *reinterpret_cast<bf16x8*>(out + toff(row, k, DIMK)) = v;
}

// ---------------- single transpose: fp32 [KD][JD] -> bf16 chunked [JD][KD] ----------------
template <int KD, int JD>
__global__ __launch_bounds__(256) void trans_tiled_kernel(const float* __restrict__ in, u16* __restrict__ out) {
    __shared__ float tile[64 * 65];
    const int t = threadIdx.x;
    const float* ib = in + (size_t)blockIdx.z * KD * JD;
    u16* ob = out + (size_t)blockIdx.z * KD * JD;
    const int j0 = blockIdx.x * 64, k0 = blockIdx.y * 64;
    {
        const int c4 = (t & 15) * 4;
#pragma unroll
        for (int i = 0; i < 4; ++i) {
            const int r = (t >> 4) + i * 16;
            float4 v = *reinterpret_cast<const float4*>(&ib[(size_t)(k0 + r) * JD + j0 + c4]);
            tile[r * 65 + c4 + 0] = v.x;
            tile[r * 65 + c4 + 1] = v.y;
            tile[r * 65 + c4 + 2] = v.z;
            tile[r * 65 + c4 + 3] = v.w;
        }
    }
    __syncthreads();
    {
        const int jl = t >> 2, kh = (t & 3) * 16;
        const int n = j0 + jl;
        bf16x8 v0, v1;
#pragma unroll
        for (int j = 0; j < 8; ++j) v0[j] = (__bf16)tile[(kh + j) * 65 + jl];
#pragma unroll
        for (int j = 0; j < 8; ++j) v1[j] = (__bf16)tile[(kh + 8 + j) * 65 + jl];
        *reinterpret_cast<bf16x8*>(ob + toff(n, k0 + kh, KD)) = v0;
        *reinterpret_cast<bf16x8*>(ob + toff(n, k0 + kh + 8, KD)) = v1;
    }
}

// ---------------- cat transpose: wg,wu [KD][JD] -> Wcat chunked [2*JD][KD] ----------------
template <int KD, int JD>
__global__ __launch_bounds__(256) void cat_trans_kernel(const float* __restrict__ g0, const float* __restrict__ u0,
                                                        u16* __restrict__ out) {
    __shared__ float tile[64 * 65];
    const int t = threadIdx.x;
    const size_t so = (size_t)blockIdx.z * KD * JD;
    u16* ob = out + (size_t)blockIdx.z * (2 * (size_t)KD * JD);
    const int j0 = blockIdx.x * 32, k0 = blockIdx.y * 64;
    const int kl = t >> 2, jf = (t & 3) * 4;
#pragma unroll
    for (int s = 0; s < 2; ++s) {
        const float* src = (s ? u0 : g0) + so;
#pragma unroll
        for (int rep = 0; rep < 2; ++rep) {
            int jb = jf + rep * 16;
            float4 v = *reinterpret_cast<const float4*>(&src[(size_t)(k0 + kl) * JD + j0 + jb]);
            int nl = ((jb >> 4) << 5) + s * 16 + (jb & 15);
            tile[kl * 65 + nl + 0] = v.x;
            tile[kl * 65 + nl + 1] = v.y;
            tile[kl * 65 + nl + 2] = v.z;
            tile[kl * 65 + nl + 3] = v.w;
        }
    }
    __syncthreads();
    {
        const int nl = t >> 2, kh = (t & 3) * 16;
        const int n = 2 * j0 + nl;
        bf16x8 v0, v1;
#pragma unroll
        for (int j = 0; j < 8; ++j) v0[j] = (__bf16)tile[(kh + j) * 65 + nl];
#pragma unroll
        for (int j = 0; j < 8; ++j) v1[j] = (__bf16)tile[(kh + 8 + j) * 65 + nl];
        *reinterpret_cast<bf16x8*>(ob + toff(n, k0 + kh, KD)) = v0;
        *reinterpret_cast<bf16x8*>(ob + toff(n, k0 + kh + 8, KD)) = v1;
    }
}

// ---------------- gate ----------------
__global__ __launch_bounds__(64) void gate_kernel(const float* __restrict__ x, const float* __restrict__ gw,
                                                  int* __restrict__ counts, int* __restrict__ ids,
                                                  int* __restrict__ tok2row, float* __restrict__ wtok) {
    const int t = blockIdx.x;
    const int lane = threadIdx.x;
    __shared__ float logits[NEXP];
    const float4* xr = reinterpret_cast<const float4*>(x + (size_t)t * DIMK);
    for (int e = 0; e < NEXP; ++e) {
        const float4* gr = reinterpret_cast<const float4*>(gw + (size_t)e * DIMK);
        float acc = 0.f;
#pragma unroll
        for (int i = 0; i < DIMK / 4 / 64; ++i) {
            float4 xv = xr[lane + i * 64];
            float4 gv = gr[lane + i * 64];
            acc += xv.x * gv.x + xv.y * gv.y + xv.z * gv.z + xv.w * gv.w;
        }
#pragma unroll
        for (int s = 32; s; s >>= 1) acc += __shfl_xor(acc, s);
        if (lane == 0) logits[e] = acc;
    }
    if (lane != 0) return;
    float sc[NEXP];
#pragma unroll
    for (int e = 0; e < NEXP; ++e) sc[e] = logits[e];
    float mx = sc[0];
#pragma unroll
    for (int e = 1; e < NEXP; ++e) mx = fmaxf(mx, sc[e]);
    float ssum = 0.f;
#pragma unroll
    for (int e = 0; e < NEXP; ++e) { sc[e] = __expf(sc[e] - mx); ssum += sc[e]; }
    const float inv = 1.f / ssum;
    float gsc[NGRP];
#pragma unroll
    for (int g = 0; g < NGRP; ++g) {
        float m2 = sc[g * 4];
#pragma unroll
        for (int j = 1; j < 4; ++j) m2 = fmaxf(m2, sc[g * 4 + j]);
        gsc[g] = m2;
    }
    int gsel = 0;
    for (int r = 0; r < NTOPG; ++r) {
        float bv = -1.f; int bi = 0;
#pragma unroll
        for (int g = 0; g < NGRP; ++g) {
            bool c = (((gsel >> g) & 1) == 0) && (gsc[g] > bv);
            bv = c ? gsc[g] : bv; bi = c ? g : bi;
        }
        gsel |= (1 << bi);
    }
    float msk[NEXP];
#pragma unroll
    for (int e = 0; e < NEXP; ++e) msk[e] = ((gsel >> (e >> 2)) & 1) ? sc[e] : -1.f;
    for (int r = 0; r < NTOPK; ++r) {
        float bv = -3.f; int bi = 0;
#pragma unroll
        for (int e = 0; e < NEXP; ++e) {
            bool c = msk[e] > bv;
            bv = c ? msk[e] : bv; bi = c ? e : bi;
        }
#pragma unroll
        for (int e = 0; e < NEXP; ++e) if (e == bi) msk[e] = -2.f;
        float w = bv * inv;
        int slot = atomicAdd(&counts[bi], 1);
        ids[bi * T_TOK + slot] = t;
        tok2row[t * NTOPK + r] = (bi << 12) | slot;
        wtok[t * NTOPK + r] = w;
    }
}

__global__ void scan_kernel(const int* __restrict__ counts, int* __restrict__ poff) {
    if (threadIdx.x == 0) {
        int o = 0;
        for (int e = 0; e < NEXP; ++e) { poff[e] = o; o += (counts[e] + 127) & ~127; }
    }
}

// ================= 256x256 / BK=64 / 16-wave (4Mx4N) / 2-buf / stage-(t+2) core =================
// Race-free order (r9-proven): vmcnt(4)->bar1 -> dsread+MFMA (2 n-half phases) -> bar2 -> STGALL(t+2,buf).
// A-side staged with per-lane global addresses (gather-capable); LDS dest linear.

// GEMM1 fused: expert (z<32, A gathered from xbT via ids) + shared (z>=32).
__global__ __launch_bounds__(1024, 1) void gemm1_fused_kernel(
    const u16* __restrict__ xbT, const u16* __restrict__ WcatE, u16* __restrict__ H,
    const u16* __restrict__ WcatS, u16* __restrict__ Hs,
    const int* __restrict__ counts, const int* __restrict__ poff, const int* __restrict__ ids) {
    __shared__ u16 Alds[2 * 16384];
    __shared__ u16 Blds[2 * 16384];
    constexpr int NT = DIMK / 64;  // 32

    int bm, bn, M, Mpad, hbase, HKdim, e = 0;
    const u16* b0;
    u16* ho;
    bool gath;
    if (blockIdx.z < 32) {
        int lin = blockIdx.x + 16 * (blockIdx.y + 8 * blockIdx.z);   // grid (16,8,32)
        e = 31 - (((lin >> 10) << 3) | (lin & 7));                   // XCD-pinned, reversed
        int j = (lin >> 3) & 127;
        bm = j & 15; bn = j >> 4;                                    // bn 0..7
        M = counts[e];
        if (bm * 256 >= M) return;
        Mpad = (M + 127) & ~127;
        hbase = poff[e];
        b0 = WcatE + (size_t)e * 2048 * DIMK;
        ho = H; HKdim = INTERN; gath = true;
    } else {
        int lin = blockIdx.x + 16 * (blockIdx.y + 8 * (blockIdx.z - 32));  // 0..255
        int swz = (lin & 7) * 32 + (lin >> 3);                              // bijective
        bm = swz & 15; bn = swz >> 4;                                       // bn 0..15
        M = T_TOK; Mpad = T_TOK; hbase = 0;
        b0 = WcatS; ho = Hs; HKdim = SINTER; gath = false;
    }

    const int tid = threadIdx.x;
    const int srow = tid >> 3, sp = tid & 7;
    size_t aSrc[2];
#pragma unroll
    for (int h = 0; h < 2; ++h) {
        int row = bm * 256 + h * 128 + srow;
        int tok;
        if (gath) { int cr = row < M ? row : M - 1; tok = ids[e * T_TOK + cr]; }
        else tok = row;
        int gsw = sp ^ (srow & 7) ^ (tok & 7);
        aSrc[h] = (size_t)(tok >> 7) * (128 * 2048) + (size_t)((tok & 127) * 64 + (gsw << 3));
    }
    const u16* bCh[2] = { b0 + (size_t)(2 * bn + 0) * (128 * 2048), b0 + (size_t)(2 * bn + 1) * (128 * 2048) };
    const int t8 = tid * 8;

    const int lane = tid & 63, wv = tid >> 6;
    const int wr = wv >> 2, wc = wv & 3;           // 4M x 4N waves
    const int l15 = lane & 15, lk = lane >> 4;

    f32x4 acc[4][4];
#pragma unroll
    for (int m = 0; m < 4; ++m)
#pragma unroll
        for (int n = 0; n < 4; ++n) acc[m][n] = {0.f, 0.f, 0.f, 0.f};

    auto STGALL = [&](int kt, int buf) {
        glds16(xbT + aSrc[0] + (size_t)kt * 8192, &Alds[buf * 16384 + t8]);
        glds16(xbT + aSrc[1] + (size_t)kt * 8192, &Alds[buf * 16384 + 8192 + t8]);
        glds16(bCh[0] + (size_t)kt * 8192 + t8, &Blds[buf * 16384 + t8]);
        glds16(bCh[1] + (size_t)kt * 8192 + t8, &Blds[buf * 16384 + 8192 + t8]);
    };
    bf16x8 afr[4][2], bfr[2][2];
    auto DSRA = [&](int buf) {
#pragma unroll
        for (int mi = 0; mi < 4; ++mi)
#pragma unroll
            for (int ki = 0; ki < 2; ++ki) {
                int rl = wr * 64 + mi * 16 + l15;
                int g = ki * 4 + lk;
                afr[mi][ki] = *reinterpret_cast<const bf16x8*>(
                    &Alds[buf * 16384 + (rl >> 7) * 8192 + (rl & 127) * 64 + ((g ^ (rl & 7)) << 3)]);
            }
    };
    auto DSRB = [&](int buf, int nh) {
#pragma unroll
        for (int nj = 0; nj < 2; ++nj)
#pragma unroll
            for (int ki = 0; ki < 2; ++ki) {
                int rc = wc * 64 + (nh * 2 + nj) * 16 + l15;
                int g = ki * 4 + lk;
                bfr[nj][ki] = *reinterpret_cast<const bf16x8*>(
                    &Blds[buf * 16384 + (rc >> 7) * 8192 + (rc & 127) * 64 + ((g ^ (rc & 7)) << 3)]);
            }
    };

    STGALL(0, 0);
    STGALL(1, 1);

#pragma unroll 1
    for (int i = 0; i < NT; ++i) {
        const int buf = i & 1;
        if (i + 1 < NT) {
            asm volatile("s_waitcnt vmcnt(4)" ::: "memory");
        } else {
            asm volatile("s_waitcnt vmcnt(0)" ::: "memory");
        }
        __builtin_amdgcn_s_barrier();           // tile i landed for all waves
        __builtin_amdgcn_sched_barrier(0);
        DSRA(buf);
        DSRB(buf, 0);
        __builtin_amdgcn_s_setprio(1);
#pragma unroll
        for (int ki = 0; ki < 2; ++ki)
#pragma unroll
            for (int mi = 0; mi < 4; ++mi)
#pragma unroll
                for (int nj = 0; nj < 2; ++nj)
                    acc[mi][nj] = __builtin_amdgcn_mfma_f32_16x16x32_bf16(afr[mi][ki], bfr[nj][ki], acc[mi][nj], 0, 0, 0);
        __builtin_amdgcn_s_setprio(0);
        DSRB(buf, 1);
        __builtin_amdgcn_s_setprio(1);
#pragma unroll
        for (int ki = 0; ki < 2; ++ki)
#pragma unroll
            for (int mi = 0; mi < 4; ++mi)
#pragma unroll
                for (int nj = 0; nj < 2; ++nj)
                    acc[mi][2 + nj] = __builtin_amdgcn_mfma_f32_16x16x32_bf16(afr[mi][ki], bfr[nj][ki], acc[mi][2 + nj], 0, 0, 0);
        __builtin_amdgcn_s_setprio(0);
        __builtin_amdgcn_sched_barrier(0);
        __builtin_amdgcn_s_barrier();           // all reads of buf complete
        __builtin_amdgcn_sched_barrier(0);
        if (i + 2 < NT) STGALL(i + 2, buf);     // safe overwrite
    }

    // epilogue: h = silu(g)*u -> H chunked
#pragma unroll
    for (int mi = 0; mi < 4; ++mi) {
#pragma unroll
        for (int r = 0; r < 4; ++r) {
            int grow = bm * 256 + wr * 64 + mi * 16 + lk * 4 + r;
            if (grow < Mpad) {
#pragma unroll
                for (int nh = 0; nh < 2; ++nh) {
                    float gg = acc[mi][nh * 2 + 0][r];
                    float uu = acc[mi][nh * 2 + 1][r];
                    float h = gg / (1.f + __expf(-gg)) * uu;
                    int n = bn * 256 + wc * 64 + nh * 32 + l15;
                    int jcol = ((n >> 5) << 4) + (n & 15);
                    __bf16 hb = (__bf16)h;
                    ho[toff(hbase + grow, jcol, HKdim)] = __builtin_bit_cast(u16, hb);
                }
            }
        }
    }
}

// GEMM2 fused: expert (z<32) -> Ye rows; shared (z>=32) K-split -> Yss slices. N=2048 both.
__global__ __launch_bounds__(1024, 1) void gemm2_fused_kernel(
    const u16* __restrict__ H, const u16* __restrict__ wdT, u16* __restrict__ Ye,
    const u16* __restrict__ Hs, const u16* __restrict__ swdT, u16* __restrict__ Yss,
    const int* __restrict__ counts, const int* __restrict__ poff) {
    __shared__ u16 Alds[2 * 16384];
    __shared__ u16 Blds[2 * 16384];
    constexpr int NT = 16;

    int bm, bn, M, rowbase, AKK, kt0;
    const u16 *aBase, *bBase;
    u16* yo;
    if (blockIdx.z < 32) {
        int lin = blockIdx.x + 16 * (blockIdx.y + 8 * blockIdx.z);
        int e = 31 - (((lin >> 10) << 3) | (lin & 7));
        int j = (lin >> 3) & 127;
        bm = j & 15; bn = j >> 4;                   // bn 0..7
        M = counts[e];
        if (bm * 256 >= M) return;
        rowbase = poff[e];
        aBase = H + (size_t)poff[e] * INTERN;
        bBase = wdT + (size_t)e * 2048 * INTERN;
        yo = Ye; AKK = INTERN; kt0 = 0;
    } else {
        int lin = blockIdx.x + 16 * (blockIdx.y + 8 * (blockIdx.z - 32));  // 0..255
        int swz = (lin & 7) * 32 + (lin >> 3);
        bm = swz & 15; bn = (swz >> 4) & 7;
        int ks = swz >> 7;
        M = T_TOK; rowbase = ks * T_TOK;
        aBase = Hs; bBase = swdT; yo = Yss; AKK = SINTER; kt0 = ks * 16;
    }
    const u16* aCh[2] = { aBase + (size_t)(2 * bm + 0) * (size_t)(128 * AKK) + (size_t)kt0 * 8192,
                          aBase + (size_t)(2 * bm + 1) * (size_t)(128 * AKK) + (size_t)kt0 * 8192 };
    const u16* bCh[2] = { bBase + (size_t)(2 * bn + 0) * (size_t)(128 * AKK) + (size_t)kt0 * 8192,
                          bBase + (size_t)(2 * bn + 1) * (size_t)(128 * AKK) + (size_t)kt0 * 8192 };
    const int tid = threadIdx.x;
    const int t8 = tid * 8;
    const int lane = tid & 63, wv = tid >> 6;
    const int wr = wv >> 2, wc = wv & 3;
    const int l15 = lane & 15, lk = lane >> 4;

    f32x4 acc[4][4];
#pragma unroll
    for (int m = 0; m < 4; ++m)
#pragma unroll
        for (int n = 0; n < 4; ++n) acc[m][n] = {0.f, 0.f, 0.f, 0.f};

    auto STGALL = [&](int kt, int buf) {
        glds16(aCh[0] + (size_t)kt * 8192 + t8, &Alds[buf * 16384 + t8]);
        glds16(aCh[1] + (size_t)kt * 8192 + t8, &Alds[buf * 16384 + 8192 + t8]);
        glds16(bCh[0] + (size_t)kt * 8192 + t8, &Blds[buf * 16384 + t8]);
        glds16(bCh[1] + (size_t)kt * 8192 + t8, &Blds[buf * 16384 + 8192 + t8]);
    };
    bf16x8 afr[4][2], bfr[2][2];
    auto DSRA = [&](int buf) {
#pragma unroll
        for (int mi = 0; mi < 4; ++mi)
#pragma unroll
            for (int ki = 0; ki < 2; ++ki) {
                int rl = wr * 64 + mi * 16 + l15;
                int g = ki * 4 + lk;
                afr[mi][ki] = *reinterpret_cast<const bf16x8*>(
                    &Alds[buf * 16384 + (rl >> 7) * 8192 + (rl & 127) * 64 + ((g ^ (rl & 7)) << 3)]);
            }
    };
    auto DSRB = [&](int buf, int nh) {
#pragma unroll
        for (int nj = 0; nj < 2; ++nj)
#pragma unroll
            for (int ki = 0; ki < 2; ++ki) {
                int rc = wc * 64 + (nh * 2 + nj) * 16 + l15;
                int g = ki * 4 + lk;
                bfr[nj][ki] = *reinterpret_cast<const bf16x8*>(
                    &Blds[buf * 16384 + (rc >> 7) * 8192 + (rc & 127) * 64 + ((g ^ (rc & 7)) << 3)]);
            }
    };

    STGALL(0, 0);
    STGALL(1, 1);

#pragma unroll 1
    for (int i = 0; i < NT; ++i) {
        const int buf = i & 1;
        if (i + 1 < NT) {
            asm volatile("s_waitcnt vmcnt(4)" ::: "memory");
        } else {
            asm volatile("s_waitcnt vmcnt(0)" ::: "memory");
        }
        __builtin_amdgcn_s_barrier();
        __builtin_amdgcn_sched_barrier(0);
        DSRA(buf);
        DSRB(buf, 0);
        __builtin_amdgcn_s_setprio(1);
#pragma unroll
        for (int ki = 0; ki < 2; ++ki)
#pragma unroll
            for (int mi = 0; mi < 4; ++mi)
#pragma unroll
                for (int nj = 0; nj < 2; ++nj)
                    acc[mi][nj] = __builtin_amdgcn_mfma_f32_16x16x32_bf16(afr[mi][ki], bfr[nj][ki], acc[mi][nj], 0, 0, 0);
        __builtin_amdgcn_s_setprio(0);
        DSRB(buf, 1);
        __builtin_amdgcn_s_setprio(1);
#pragma unroll
        for (int ki = 0; ki < 2; ++ki)
#pragma unroll
            for (int mi = 0; mi < 4; ++mi)
#pragma unroll
                for (int nj = 0; nj < 2; ++nj)
                    acc[mi][2 + nj] = __builtin_amdgcn_mfma_f32_16x16x32_bf16(afr[mi][ki], bfr[nj][ki], acc[mi][2 + nj], 0, 0, 0);
        __builtin_amdgcn_s_setprio(0);
        __builtin_amdgcn_sched_barrier(0);
        __builtin_amdgcn_s_barrier();
        __builtin_amdgcn_sched_barrier(0);
        if (i + 2 < NT) STGALL(i + 2, buf);
    }

#pragma unroll
    for (int mi = 0; mi < 4; ++mi) {
#pragma unroll
        for (int r = 0; r < 4; ++r) {
            int grow = bm * 256 + wr * 64 + mi * 16 + lk * 4 + r;
            if (grow < M) {
                u16* yr = yo + (size_t)(rowbase + grow) * 2048;
#pragma unroll
                for (int ni = 0; ni < 4; ++ni) {
                    int col = bn * 256 + wc * 64 + ni * 16 + l15;
                    __bf16 yb = (__bf16)acc[mi][ni][r];
                    yr[col] = __builtin_bit_cast(u16, yb);
                }
            }
        }
    }
}

// ---------------- combine: out[t] = Yss0[t] + Yss1[t] + sum_r w_r * Ye[row_r] ----------------
__global__ __launch_bounds__(256) void combine_kernel(const u16* __restrict__ Yss, const u16* __restrict__ Ye,
                                                      const int* __restrict__ tok2row, const float* __restrict__ wtok,
                                                      const int* __restrict__ poff, float* __restrict__ out) {
    const int t = blockIdx.x;
    const int c = threadIdx.x * 8;
    bf16x8 v0 = *reinterpret_cast<const bf16x8*>(Yss + (size_t)t * 2048 + c);
    bf16x8 v1 = *reinterpret_cast<const bf16x8*>(Yss + (size_t)(T_TOK + t) * 2048 + c);
    float acc[8];
#pragma unroll
    for (int j = 0; j < 8; ++j) acc[j] = (float)v0[j] + (float)v1[j];
#pragma unroll
    for (int r = 0; r < NTOPK; ++r) {
        int pk = tok2row[t * NTOPK + r];
        int e = pk >> 12, sl = pk & 4095;
        int row = poff[e] + sl;
        float w = wtok[t * NTOPK + r];
        bf16x8 v = *reinterpret_cast<const bf16x8*>(Ye + (size_t)row * 2048 + c);
#pragma unroll
        for (int j = 0; j < 8; ++j) acc[j] += w * (float)v[j];
    }
    float4 o0 = {acc[0], acc[1], acc[2], acc[3]};
    float4 o1 = {acc[4], acc[5], acc[6], acc[7]};
    float4* po = reinterpret_cast<float4*>(out + (size_t)t * 2048 + c);
    po[0] = o0; po[1] = o1;
}

extern "C" void kernel_launch(void* const* d_in, const int* in_sizes, int n_in,
                              void* d_out, int out_size, void* d_ws, size_t ws_size,
                              hipStream_t stream) {
    const float* x = (const float*)d_in[0];
    const float* gate_w = (const float*)d_in[1];
    const float* wg = (const float*)d_in[2];
    const float* wu = (const float*)d_in[3];
    const float* wd = (const float*)d_in[4];
    const float* swg = (const float*)d_in[5];
    const float* swu = (const float*)d_in[6];
    const float* swd = (const float*)d_in[7];
    float* out = (float*)d_out;

    char* ws = (char*)d_ws;
    size_t off = 0;
    auto alloc = [&](size_t bytes) {
        void* p = ws + off;
        off = (off + bytes + 255) & ~(size_t)255;
        return p;
    };
    u16* xbT = (u16*)alloc((size_t)T_TOK * DIMK * 2);                  // 16.8 MB
    u16* H = (u16*)alloc((size_t)MAXPADROWS * INTERN * 2);             // 59.8 MB
    u16* Hs = (u16*)alloc((size_t)T_TOK * SINTER * 2);                 // 16.8 MB
    u16* Ye = (u16*)alloc((size_t)MAXPADROWS * 2048 * 2);              // 119.6 MB
    u16* Yss = (u16*)alloc((size_t)2 * T_TOK * 2048 * 2);              // 33.6 MB
    int* ids = (int*)alloc((size_t)NEXP * T_TOK * 4);
    int* tok2row = (int*)alloc((size_t)T_TOK * NTOPK * 4);
    float* wtok = (float*)alloc((size_t)T_TOK * NTOPK * 4);
    int* counts = (int*)alloc(NEXP * 4);
    int* poff = (int*)alloc(NEXP * 4);
    u16* WcatS = (u16*)alloc((size_t)(2 * SINTER) * DIMK * 2);         // 16.8 MB
    u16* swdT = (u16*)alloc((size_t)DIMK * SINTER * 2);                // 8.4 MB
    u16* WcatE = (u16*)alloc((size_t)NEXP * (2 * INTERN) * DIMK * 2);  // 268.4 MB
    u16* wdT = WcatE;  // alias: wd transpose runs after GEMM1 consumed WcatE (stream-ordered)

    hipMemsetAsync(counts, 0, NEXP * 4, stream);
    cast_x_tiled_kernel<<<(T_TOK * DIMK) / (256 * 8), 256, 0, stream>>>(x, xbT);
    gate_kernel<<<T_TOK, 64, 0, stream>>>(x, gate_w, counts, ids, tok2row, wtok);
    scan_kernel<<<1, 64, 0, stream>>>(counts, poff);

    // weight reshapes
    cat_trans_kernel<DIMK, SINTER><<<dim3(SINTER / 32, DIMK / 64, 1), 256, 0, stream>>>(swg, swu, WcatS);
    cat_trans_kernel<DIMK, INTERN><<<dim3(INTERN / 32, DIMK / 64, NEXP), 256, 0, stream>>>(wg, wu, WcatE);
    trans_tiled_kernel<SINTER, DIMK><<<dim3(DIMK / 64, SINTER / 64, 1), 256, 0, stream>>>(swd, swdT);

    // fused GEMM1 (256x256, 16 waves, gather-free expert A from xbT)
    gemm1_fused_kernel<<<dim3(16, 8, 34), 1024, 0, stream>>>(
        xbT, WcatE, H, WcatS, Hs, counts, poff, ids);

    // wd transpose into aliased WcatE region (GEMM1 done by stream order)
    trans_tiled_kernel<INTERN, DIMK><<<dim3(DIMK / 64, INTERN / 64, NEXP), 256, 0, stream>>>(wd, wdT);

    // fused GEMM2 (256x256, 16 waves): expert -> Ye; shared K-split -> Yss
    gemm2_fused_kernel<<<dim3(16, 8, 34), 1024, 0, stream>>>(
        H, wdT, Ye, Hs, swdT, Yss, counts, poff);

    // final combine -> out
    combine_kernel<<<T_TOK, 256, 0, stream>>>(Yss, Ye, tok2row, wtok, poff, out);
}

// Round 12
// 1034.268 us; speedup vs baseline: 1.2864x; 1.0994x over previous
//
#include <hip/hip_runtime.h>
#include <hip/hip_bf16.h>

typedef float f32x4 __attribute__((ext_vector_type(4)));
typedef __bf16 bf16x8 __attribute__((ext_vector_type(8)));
typedef unsigned short u16;

#define T_TOK 4096
#define DIMK 2048
#define INTERN 1024
#define NEXP 32
#define NTOPK 6
#define NGRP 8
#define NTOPG 4
#define SINTER 2048
#define MAXPADROWS 29184

__device__ __forceinline__ void glds16(const void* g, void* l) {
    auto* gp = (const __attribute__((address_space(1))) int*)(g);
    auto* lp = (__attribute__((address_space(3))) int*)(l);
    __builtin_amdgcn_global_load_lds(gp, lp, 16, 0, 0);
}

// Chunked+swizzled layout for [Rows][K] bf16: row-chunks 128, k-chunks 64.
// In-chunk (16KB=8192 elems): off = row*64 + ((g ^ (row&7))<<3) + (k&7), g=(k>>3)&7.
__device__ __forceinline__ size_t toff(int row, int k, int K) {
    int g = (k >> 3) & 7;
    return (size_t)(row >> 7) * (size_t)(128 * K) + (size_t)(k >> 6) * 8192 +
           (size_t)((row & 127) * 64 + ((g ^ (row & 7)) << 3) + (k & 7));
}

// ---------------- cast x fp32 -> bf16 chunked ----------------
__global__ __launch_bounds__(256) void cast_x_tiled_kernel(const float* __restrict__ in, u16* __restrict__ out) {
    int gi = (blockIdx.x * 256 + threadIdx.x) * 8;
    int row = gi >> 11, k = gi & 2047;
    const float4* p = reinterpret_cast<const float4*>(in + gi);
    float4 a = p[0], b = p[1];
    bf16x8 v;
    v[0] = (__bf16)a.x; v[1] = (__bf16)a.y; v[2] = (__bf16)a.z; v[3] = (__bf16)a.w;
    v[4] = (__bf16)b.x; v[5] = (__bf16)b.y; v[6] = (__bf16)b.z; v[7] = (__bf16)b.w;
    *reinterpret_cast<bf16x8*>(out + toff(row, k, DIMK)) = v;
}

// ---------------- single transpose: fp32 [KD][JD] -> bf16 chunked [JD][KD] ----------------
template <int KD, int JD>
__global__ __launch_bounds__(256) void trans_tiled_kernel(const float* __restrict__ in, u16* __restrict__ out) {
    __shared__ float tile[64 * 65];
    const int t = threadIdx.x;
    const float* ib = in + (size_t)blockIdx.z * KD * JD;
    u16* ob = out + (size_t)blockIdx.z * KD * JD;
    const int j0 = blockIdx.x * 64, k0 = blockIdx.y * 64;
    {
        const int c4 = (t & 15) * 4;
#pragma unroll
        for (int i = 0; i < 4; ++i) {
            const int r = (t >> 4) + i * 16;
            float4 v = *reinterpret_cast<const float4*>(&ib[(size_t)(k0 + r) * JD + j0 + c4]);
            tile[r * 65 + c4 + 0] = v.x;
            tile[r * 65 + c4 + 1] = v.y;
            tile[r * 65 + c4 + 2] = v.z;
            tile[r * 65 + c4 + 3] = v.w;
        }
    }
    __syncthreads();
    {
        const int jl = t >> 2, kh = (t & 3) * 16;
        const int n = j0 + jl;
        bf16x8 v0, v1;
#pragma unroll
        for (int j = 0; j < 8; ++j) v0[j] = (__bf16)tile[(kh + j) * 65 + jl];
#pragma unroll
        for (int j = 0; j < 8; ++j) v1[j] = (__bf16)tile[(kh + 8 + j) * 65 + jl];
        *reinterpret_cast<bf16x8*>(ob + toff(n, k0 + kh, KD)) = v0;
        *reinterpret_cast<bf16x8*>(ob + toff(n, k0 + kh + 8, KD)) = v1;
    }
}

// ---------------- cat transpose: wg,wu [KD][JD] -> Wcat chunked [2*JD][KD] ----------------
template <int KD, int JD>
__global__ __launch_bounds__(256) void cat_trans_kernel(const float* __restrict__ g0, const float* __restrict__ u0,
                                                        u16* __restrict__ out) {
    __shared__ float tile[64 * 65];
    const int t = threadIdx.x;
    const size_t so = (size_t)blockIdx.z * KD * JD;
    u16* ob = out + (size_t)blockIdx.z * (2 * (size_t)KD * JD);
    const int j0 = blockIdx.x * 32, k0 = blockIdx.y * 64;
    const int kl = t >> 2, jf = (t & 3) * 4;
#pragma unroll
    for (int s = 0; s < 2; ++s) {
        const float* src = (s ? u0 : g0) + so;
#pragma unroll
        for (int rep = 0; rep < 2; ++rep) {
            int jb = jf + rep * 16;
            float4 v = *reinterpret_cast<const float4*>(&src[(size_t)(k0 + kl) * JD + j0 + jb]);
            int nl = ((jb >> 4) << 5) + s * 16 + (jb & 15);
            tile[kl * 65 + nl + 0] = v.x;
            tile[kl * 65 + nl + 1] = v.y;
            tile[kl * 65 + nl + 2] = v.z;
            tile[kl * 65 + nl + 3] = v.w;
        }
    }
    __syncthreads();
    {
        const int nl = t >> 2, kh = (t & 3) * 16;
        const int n = 2 * j0 + nl;
        bf16x8 v0, v1;
#pragma unroll
        for (int j = 0; j < 8; ++j) v0[j] = (__bf16)tile[(kh + j) * 65 + nl];
#pragma unroll
        for (int j = 0; j < 8; ++j) v1[j] = (__bf16)tile[(kh + 8 + j) * 65 + nl];
        *reinterpret_cast<bf16x8*>(ob + toff(n, k0 + kh, KD)) = v0;
        *reinterpret_cast<bf16x8*>(ob + toff(n, k0 + kh + 8, KD)) = v1;
    }
}

// ---------------- gate ----------------
__global__ __launch_bounds__(64) void gate_kernel(const float* __restrict__ x, const float* __restrict__ gw,
                                                  int* __restrict__ counts, int* __restrict__ ids,
                                                  int* __restrict__ tok2row, float* __restrict__ wtok) {
    const int t = blockIdx.x;
    const int lane = threadIdx.x;
    __shared__ float logits[NEXP];
    const float4* xr = reinterpret_cast<const float4*>(x + (size_t)t * DIMK);
    for (int e = 0; e < NEXP; ++e) {
        const float4* gr = reinterpret_cast<const float4*>(gw + (size_t)e * DIMK);
        float acc = 0.f;
#pragma unroll
        for (int i = 0; i < DIMK / 4 / 64; ++i) {
            float4 xv = xr[lane + i * 64];
            float4 gv = gr[lane + i * 64];
            acc += xv.x * gv.x + xv.y * gv.y + xv.z * gv.z + xv.w * gv.w;
        }
#pragma unroll
        for (int s = 32; s; s >>= 1) acc += __shfl_xor(acc, s);
        if (lane == 0) logits[e] = acc;
    }
    if (lane != 0) return;
    float sc[NEXP];
#pragma unroll
    for (int e = 0; e < NEXP; ++e) sc[e] = logits[e];
    float mx = sc[0];
#pragma unroll
    for (int e = 1; e < NEXP; ++e) mx = fmaxf(mx, sc[e]);
    float ssum = 0.f;
#pragma unroll
    for (int e = 0; e < NEXP; ++e) { sc[e] = __expf(sc[e] - mx); ssum += sc[e]; }
    const float inv = 1.f / ssum;
    float gsc[NGRP];
#pragma unroll
    for (int g = 0; g < NGRP; ++g) {
        float m2 = sc[g * 4];
#pragma unroll
        for (int j = 1; j < 4; ++j) m2 = fmaxf(m2, sc[g * 4 + j]);
        gsc[g] = m2;
    }
    int gsel = 0;
    for (int r = 0; r < NTOPG; ++r) {
        float bv = -1.f; int bi = 0;
#pragma unroll
        for (int g = 0; g < NGRP; ++g) {
            bool c = (((gsel >> g) & 1) == 0) && (gsc[g] > bv);
            bv = c ? gsc[g] : bv; bi = c ? g : bi;
        }
        gsel |= (1 << bi);
    }
    float msk[NEXP];
#pragma unroll
    for (int e = 0; e < NEXP; ++e) msk[e] = ((gsel >> (e >> 2)) & 1) ? sc[e] : -1.f;
    for (int r = 0; r < NTOPK; ++r) {
        float bv = -3.f; int bi = 0;
#pragma unroll
        for (int e = 0; e < NEXP; ++e) {
            bool c = msk[e] > bv;
            bv = c ? msk[e] : bv; bi = c ? e : bi;
        }
#pragma unroll
        for (int e = 0; e < NEXP; ++e) if (e == bi) msk[e] = -2.f;
        float w = bv * inv;
        int slot = atomicAdd(&counts[bi], 1);
        ids[bi * T_TOK + slot] = t;
        tok2row[t * NTOPK + r] = (bi << 12) | slot;
        wtok[t * NTOPK + r] = w;
    }
}

__global__ void scan_kernel(const int* __restrict__ counts, int* __restrict__ poff) {
    if (threadIdx.x == 0) {
        int o = 0;
        for (int e = 0; e < NEXP; ++e) { poff[e] = o; o += (counts[e] + 127) & ~127; }
    }
}

// ================= 256x256 / BK=64 / 8-wave (2M x 4N) / m201 8-phase core =================
// Per K-tile t (buf=t&1), quadrant phases:
//  ph0: dsrA(m0,8)+dsrB0(n0,4); SA(t+1,half1,buf^1); bar; 16 MFMA m0n0; bar
//  ph1: dsrB1(n1,4);            SB(t+1,half0,buf^1); bar; 16 MFMA m0n1; bar
//  ph2: dsrA(m1,8);             SB(t+1,half1,buf^1); bar; 16 MFMA m1n1; bar
//  ph3: (no reads)              SA(t+2,half0,buf);        16 MFMA m1n0; vmcnt(2); bar
// Ledger: every stage target dead >=1 barrier prior; vmcnt(2)+bar proves tile t+1 landed.

// GEMM1 fused: expert (z<32, gather-A from xbT via ids) + shared (z>=32).
__global__ __launch_bounds__(512, 2) void gemm1_fused_kernel(
    const u16* __restrict__ xbT, const u16* __restrict__ WcatE, u16* __restrict__ H,
    const u16* __restrict__ WcatS, u16* __restrict__ Hs,
    const int* __restrict__ counts, const int* __restrict__ poff, const int* __restrict__ ids) {
    __shared__ u16 Alds[2 * 16384];
    __shared__ u16 Blds[2 * 16384];
    constexpr int NT = DIMK / 64;  // 32

    int bm, bn, M, Mpad, hbase, HKdim, e = 0;
    const u16* b0;
    u16* ho;
    bool gath;
    if (blockIdx.z < 32) {
        int lin = blockIdx.x + 16 * (blockIdx.y + 8 * blockIdx.z);
        e = 31 - (((lin >> 10) << 3) | (lin & 7));
        int j = (lin >> 3) & 127;
        bm = j & 15; bn = j >> 4;
        M = counts[e];
        if (bm * 256 >= M) return;
        Mpad = (M + 127) & ~127;
        hbase = poff[e];
        b0 = WcatE + (size_t)e * 2048 * DIMK;
        ho = H; HKdim = INTERN; gath = true;
    } else {
        int lin = blockIdx.x + 16 * (blockIdx.y + 8 * (blockIdx.z - 32));
        int swz = (lin & 7) * 32 + (lin >> 3);
        bm = swz & 15; bn = swz >> 4;
        M = T_TOK; Mpad = T_TOK; hbase = 0;
        b0 = WcatS; ho = Hs; HKdim = SINTER; gath = false;
    }

    const int tid = threadIdx.x;
    const int t8 = tid * 8;  // 0..4088
    // A source addresses: half h in {0,1}, sub j in {0,1}: dest row = h*128 + j*64 + (tid>>3)
    size_t aSrc[2][2];
#pragma unroll
    for (int h = 0; h < 2; ++h)
#pragma unroll
        for (int j = 0; j < 2; ++j) {
            int drow = j * 64 + (tid >> 3);
            int row = bm * 256 + h * 128 + drow;
            int tok;
            if (gath) { int cr = row < M ? row : M - 1; tok = ids[e * T_TOK + cr]; }
            else tok = row;
            int slot = (tid & 7) ^ (drow & 7) ^ (tok & 7);
            aSrc[h][j] = (size_t)(tok >> 7) * (size_t)(128 * 2048) + (size_t)((tok & 127) * 64 + slot * 8);
        }
    const u16* bCh[2] = { b0 + (size_t)(2 * bn + 0) * (128 * 2048), b0 + (size_t)(2 * bn + 1) * (128 * 2048) };

    const int lane = tid & 63, wv = tid >> 6;
    const int wr = wv >> 2, wc = wv & 3;    // 2M x 4N
    const int l15 = lane & 15, lk = lane >> 4;

    f32x4 acc[8][4];
#pragma unroll
    for (int m = 0; m < 8; ++m)
#pragma unroll
        for (int n = 0; n < 4; ++n) acc[m][n] = {0.f, 0.f, 0.f, 0.f};

    auto SA = [&](int kt, int h, int buf) {
        glds16(xbT + aSrc[h][0] + (size_t)kt * 8192, &Alds[buf * 16384 + h * 8192 + t8]);
        glds16(xbT + aSrc[h][1] + (size_t)kt * 8192, &Alds[buf * 16384 + h * 8192 + 4096 + t8]);
    };
    auto SB = [&](int kt, int h, int buf) {
        glds16(bCh[h] + (size_t)kt * 8192 + t8, &Blds[buf * 16384 + h * 8192 + t8]);
        glds16(bCh[h] + (size_t)kt * 8192 + 4096 + t8, &Blds[buf * 16384 + h * 8192 + 4096 + t8]);
    };
    bf16x8 afr[4][2], bfr0[2][2], bfr1[2][2];
    auto DSRA = [&](int buf, int mh) {
#pragma unroll
        for (int mi = 0; mi < 4; ++mi)
#pragma unroll
            for (int ki = 0; ki < 2; ++ki) {
                int rl = wr * 128 + mh * 64 + mi * 16 + l15;
                int g = ki * 4 + lk;
                afr[mi][ki] = *reinterpret_cast<const bf16x8*>(
                    &Alds[buf * 16384 + (rl >> 7) * 8192 + (rl & 127) * 64 + ((g ^ (rl & 7)) << 3)]);
            }
    };
    auto DSRB = [&](int buf, int nh, bf16x8 (&bf)[2][2]) {
#pragma unroll
        for (int nj = 0; nj < 2; ++nj)
#pragma unroll
            for (int ki = 0; ki < 2; ++ki) {
                int rc = wc * 64 + (nh * 2 + nj) * 16 + l15;
                int g = ki * 4 + lk;
                bf[nj][ki] = *reinterpret_cast<const bf16x8*>(
                    &Blds[buf * 16384 + (rc >> 7) * 8192 + (rc & 127) * 64 + ((g ^ (rc & 7)) << 3)]);
            }
    };

    // prologue: tile 0 (4 halves) + tile1 A0; vmcnt(2) leaves only S(1,A0) in flight
    SA(0, 0, 0); SA(0, 1, 0); SB(0, 0, 0); SB(0, 1, 0); SA(1, 0, 1);
    asm volatile("s_waitcnt vmcnt(2)" ::: "memory");
    __builtin_amdgcn_s_barrier();

#pragma unroll 1
    for (int t = 0; t < NT; ++t) {
        const int buf = t & 1;
        // ph0: m0 x n0
        DSRA(buf, 0);
        DSRB(buf, 0, bfr0);
        if (t + 1 < NT) SA(t + 1, 1, buf ^ 1);
        __builtin_amdgcn_s_barrier();
        __builtin_amdgcn_s_setprio(1);
#pragma unroll
        for (int ki = 0; ki < 2; ++ki)
#pragma unroll
            for (int mi = 0; mi < 4; ++mi)
#pragma unroll
                for (int nj = 0; nj < 2; ++nj)
                    acc[mi][nj] = __builtin_amdgcn_mfma_f32_16x16x32_bf16(afr[mi][ki], bfr0[nj][ki], acc[mi][nj], 0, 0, 0);
        __builtin_amdgcn_s_setprio(0);
        __builtin_amdgcn_s_barrier();
        // ph1: m0 x n1
        DSRB(buf, 1, bfr1);
        if (t + 1 < NT) SB(t + 1, 0, buf ^ 1);
        __builtin_amdgcn_s_barrier();
        __builtin_amdgcn_s_setprio(1);
#pragma unroll
        for (int ki = 0; ki < 2; ++ki)
#pragma unroll
            for (int mi = 0; mi < 4; ++mi)
#pragma unroll
                for (int nj = 0; nj < 2; ++nj)
                    acc[mi][2 + nj] = __builtin_amdgcn_mfma_f32_16x16x32_bf16(afr[mi][ki], bfr1[nj][ki], acc[mi][2 + nj], 0, 0, 0);
        __builtin_amdgcn_s_setprio(0);
        __builtin_amdgcn_s_barrier();
        // ph2: m1 x n1
        DSRA(buf, 1);
        if (t + 1 < NT) SB(t + 1, 1, buf ^ 1);
        __builtin_amdgcn_s_barrier();
        __builtin_amdgcn_s_setprio(1);
#pragma unroll
        for (int ki = 0; ki < 2; ++ki)
#pragma unroll
            for (int mi = 0; mi < 4; ++mi)
#pragma unroll
                for (int nj = 0; nj < 2; ++nj)
                    acc[4 + mi][2 + nj] = __builtin_amdgcn_mfma_f32_16x16x32_bf16(afr[mi][ki], bfr1[nj][ki], acc[4 + mi][2 + nj], 0, 0, 0);
        __builtin_amdgcn_s_setprio(0);
        __builtin_amdgcn_s_barrier();
        // ph3: m1 x n0 (no ds reads; bfr0 retained)
        if (t + 2 < NT) SA(t + 2, 0, buf);
        __builtin_amdgcn_s_setprio(1);
#pragma unroll
        for (int ki = 0; ki < 2; ++ki)
#pragma unroll
            for (int mi = 0; mi < 4; ++mi)
#pragma unroll
                for (int nj = 0; nj < 2; ++nj)
                    acc[4 + mi][nj] = __builtin_amdgcn_mfma_f32_16x16x32_bf16(afr[mi][ki], bfr0[nj][ki], acc[4 + mi][nj], 0, 0, 0);
        __builtin_amdgcn_s_setprio(0);
        if (t + 2 < NT) { asm volatile("s_waitcnt vmcnt(2)" ::: "memory"); }
        else { asm volatile("s_waitcnt vmcnt(0)" ::: "memory"); }
        __builtin_amdgcn_s_barrier();
    }

    // epilogue: h = silu(g)*u -> H chunked
#pragma unroll
    for (int mI = 0; mI < 8; ++mI) {
#pragma unroll
        for (int r = 0; r < 4; ++r) {
            int grow = bm * 256 + wr * 128 + mI * 16 + lk * 4 + r;
            if (grow < Mpad) {
#pragma unroll
                for (int nh = 0; nh < 2; ++nh) {
                    float gg = acc[mI][nh * 2 + 0][r];
                    float uu = acc[mI][nh * 2 + 1][r];
                    float h = gg / (1.f + __expf(-gg)) * uu;
                    int n = bn * 256 + wc * 64 + nh * 32 + l15;
                    int jcol = ((n >> 5) << 4) + (n & 15);
                    __bf16 hb = (__bf16)h;
                    ho[toff(hbase + grow, jcol, HKdim)] = __builtin_bit_cast(u16, hb);
                }
            }
        }
    }
}

// GEMM2 fused: expert (z<32) -> Ye rows; shared (z>=32) K-split -> Yss slices.
__global__ __launch_bounds__(512, 2) void gemm2_fused_kernel(
    const u16* __restrict__ H, const u16* __restrict__ wdT, u16* __restrict__ Ye,
    const u16* __restrict__ Hs, const u16* __restrict__ swdT, u16* __restrict__ Yss,
    const int* __restrict__ counts, const int* __restrict__ poff) {
    __shared__ u16 Alds[2 * 16384];
    __shared__ u16 Blds[2 * 16384];
    constexpr int NT = 16;

    int bm, bn, M, rowbase, AKK, kt0;
    const u16 *aBase, *bBase;
    u16* yo;
    if (blockIdx.z < 32) {
        int lin = blockIdx.x + 16 * (blockIdx.y + 8 * blockIdx.z);
        int e = 31 - (((lin >> 10) << 3) | (lin & 7));
        int j = (lin >> 3) & 127;
        bm = j & 15; bn = j >> 4;
        M = counts[e];
        if (bm * 256 >= M) return;
        rowbase = poff[e];
        aBase = H + (size_t)poff[e] * INTERN;
        bBase = wdT + (size_t)e * 2048 * INTERN;
        yo = Ye; AKK = INTERN; kt0 = 0;
    } else {
        int lin = blockIdx.x + 16 * (blockIdx.y + 8 * (blockIdx.z - 32));
        int swz = (lin & 7) * 32 + (lin >> 3);
        bm = swz & 15; bn = (swz >> 4) & 7;
        int ks = swz >> 7;
        M = T_TOK; rowbase = ks * T_TOK;
        aBase = Hs; bBase = swdT; yo = Yss; AKK = SINTER; kt0 = ks * 16;
    }
    const u16* aCh[2] = { aBase + (size_t)(2 * bm + 0) * (size_t)(128 * AKK) + (size_t)kt0 * 8192,
                          aBase + (size_t)(2 * bm + 1) * (size_t)(128 * AKK) + (size_t)kt0 * 8192 };
    const u16* bCh[2] = { bBase + (size_t)(2 * bn + 0) * (size_t)(128 * AKK) + (size_t)kt0 * 8192,
                          bBase + (size_t)(2 * bn + 1) * (size_t)(128 * AKK) + (size_t)kt0 * 8192 };
    const int tid = threadIdx.x;
    const int t8 = tid * 8;
    const int lane = tid & 63, wv = tid >> 6;
    const int wr = wv >> 2, wc = wv & 3;
    const int l15 = lane & 15, lk = lane >> 4;

    f32x4 acc[8][4];
#pragma unroll
    for (int m = 0; m < 8; ++m)
#pragma unroll
        for (int n = 0; n < 4; ++n) acc[m][n] = {0.f, 0.f, 0.f, 0.f};

    auto SA = [&](int kt, int h, int buf) {
        glds16(aCh[h] + (size_t)kt * 8192 + t8, &Alds[buf * 16384 + h * 8192 + t8]);
        glds16(aCh[h] + (size_t)kt * 8192 + 4096 + t8, &Alds[buf * 16384 + h * 8192 + 4096 + t8]);
    };
    auto SB = [&](int kt, int h, int buf) {
        glds16(bCh[h] + (size_t)kt * 8192 + t8, &Blds[buf * 16384 + h * 8192 + t8]);
        glds16(bCh[h] + (size_t)kt * 8192 + 4096 + t8, &Blds[buf * 16384 + h * 8192 + 4096 + t8]);
    };
    bf16x8 afr[4][2], bfr0[2][2], bfr1[2][2];
    auto DSRA = [&](int buf, int mh) {
#pragma unroll
        for (int mi = 0; mi < 4; ++mi)
#pragma unroll
            for (int ki = 0; ki < 2; ++ki) {
                int rl = wr * 128 + mh * 64 + mi * 16 + l15;
                int g = ki * 4 + lk;
                afr[mi][ki] = *reinterpret_cast<const bf16x8*>(
                    &Alds[buf * 16384 + (rl >> 7) * 8192 + (rl & 127) * 64 + ((g ^ (rl & 7)) << 3)]);
            }
    };
    auto DSRB = [&](int buf, int nh, bf16x8 (&bf)[2][2]) {
#pragma unroll
        for (int nj = 0; nj < 2; ++nj)
#pragma unroll
            for (int ki = 0; ki < 2; ++ki) {
                int rc = wc * 64 + (nh * 2 + nj) * 16 + l15;
                int g = ki * 4 + lk;
                bf[nj][ki] = *reinterpret_cast<const bf16x8*>(
                    &Blds[buf * 16384 + (rc >> 7) * 8192 + (rc & 127) * 64 + ((g ^ (rc & 7)) << 3)]);
            }
    };

    SA(0, 0, 0); SA(0, 1, 0); SB(0, 0, 0); SB(0, 1, 0); SA(1, 0, 1);
    asm volatile("s_waitcnt vmcnt(2)" ::: "memory");
    __builtin_amdgcn_s_barrier();

#pragma unroll 1
    for (int t = 0; t < NT; ++t) {
        const int buf = t & 1;
        DSRA(buf, 0);
        DSRB(buf, 0, bfr0);
        if (t + 1 < NT) SA(t + 1, 1, buf ^ 1);
        __builtin_amdgcn_s_barrier();
        __builtin_amdgcn_s_setprio(1);
#pragma unroll
        for (int ki = 0; ki < 2; ++ki)
#pragma unroll
            for (int mi = 0; mi < 4; ++mi)
#pragma unroll
                for (int nj = 0; nj < 2; ++nj)
                    acc[mi][nj] = __builtin_amdgcn_mfma_f32_16x16x32_bf16(afr[mi][ki], bfr0[nj][ki], acc[mi][nj], 0, 0, 0);
        __builtin_amdgcn_s_setprio(0);
        __builtin_amdgcn_s_barrier();
        DSRB(buf, 1, bfr1);
        if (t + 1 < NT) SB(t + 1, 0, buf ^ 1);
        __builtin_amdgcn_s_barrier();
        __builtin_amdgcn_s_setprio(1);
#pragma unroll
        for (int ki = 0; ki < 2; ++ki)
#pragma unroll
            for (int mi = 0; mi < 4; ++mi)
#pragma unroll
                for (int nj = 0; nj < 2; ++nj)
                    acc[mi][2 + nj] = __builtin_amdgcn_mfma_f32_16x16x32_bf16(afr[mi][ki], bfr1[nj][ki], acc[mi][2 + nj], 0, 0, 0);
        __builtin_amdgcn_s_setprio(0);
        __builtin_amdgcn_s_barrier();
        DSRA(buf, 1);
        if (t + 1 < NT) SB(t + 1, 1, buf ^ 1);
        __builtin_amdgcn_s_barrier();
        __builtin_amdgcn_s_setprio(1);
#pragma unroll
        for (int ki = 0; ki < 2; ++ki)
#pragma unroll
            for (int mi = 0; mi < 4; ++mi)
#pragma unroll
                for (int nj = 0; nj < 2; ++nj)
                    acc[4 + mi][2 + nj] = __builtin_amdgcn_mfma_f32_16x16x32_bf16(afr[mi][ki], bfr1[nj][ki], acc[4 + mi][2 + nj], 0, 0, 0);
        __builtin_amdgcn_s_setprio(0);
        __builtin_amdgcn_s_barrier();
        if (t + 2 < NT) SA(t + 2, 0, buf);
        __builtin_amdgcn_s_setprio(1);
#pragma unroll
        for (int ki = 0; ki < 2; ++ki)
#pragma unroll
            for (int mi = 0; mi < 4; ++mi)
#pragma unroll
                for (int nj = 0; nj < 2; ++nj)
                    acc[4 + mi][nj] = __builtin_amdgcn_mfma_f32_16x16x32_bf16(afr[mi][ki], bfr0[nj][ki], acc[4 + mi][nj], 0, 0, 0);
        __builtin_amdgcn_s_setprio(0);
        if (t + 2 < NT) { asm volatile("s_waitcnt vmcnt(2)" ::: "memory"); }
        else { asm volatile("s_waitcnt vmcnt(0)" ::: "memory"); }
        __builtin_amdgcn_s_barrier();
    }

#pragma unroll
    for (int mI = 0; mI < 8; ++mI) {
#pragma unroll
        for (int r = 0; r < 4; ++r) {
            int grow = bm * 256 + wr * 128 + mI * 16 + lk * 4 + r;
            if (grow < M) {
                u16* yr = yo + (size_t)(rowbase + grow) * 2048;
#pragma unroll
                for (int ni = 0; ni < 4; ++ni) {
                    int col = bn * 256 + wc * 64 + ni * 16 + l15;
                    __bf16 yb = (__bf16)acc[mI][ni][r];
                    yr[col] = __builtin_bit_cast(u16, yb);
                }
            }
        }
    }
}

// ---------------- combine: out[t] = Yss0[t] + Yss1[t] + sum_r w_r * Ye[row_r] ----------------
__global__ __launch_bounds__(256) void combine_kernel(const u16* __restrict__ Yss, const u16* __restrict__ Ye,
                                                      const int* __restrict__ tok2row, const float* __restrict__ wtok,
                                                      const int* __restrict__ poff, float* __restrict__ out) {
    const int t = blockIdx.x;
    const int c = threadIdx.x * 8;
    bf16x8 v0 = *reinterpret_cast<const bf16x8*>(Yss + (size_t)t * 2048 + c);
    bf16x8 v1 = *reinterpret_cast<const bf16x8*>(Yss + (size_t)(T_TOK + t) * 2048 + c);
    float acc[8];
#pragma unroll
    for (int j = 0; j < 8; ++j) acc[j] = (float)v0[j] + (float)v1[j];
#pragma unroll
    for (int r = 0; r < NTOPK; ++r) {
        int pk = tok2row[t * NTOPK + r];
        int e = pk >> 12, sl = pk & 4095;
        int row = poff[e] + sl;
        float w = wtok[t * NTOPK + r];
        bf16x8 v = *reinterpret_cast<const bf16x8*>(Ye + (size_t)row * 2048 + c);
#pragma unroll
        for (int j = 0; j < 8; ++j) acc[j] += w * (float)v[j];
    }
    float4 o0 = {acc[0], acc[1], acc[2], acc[3]};
    float4 o1 = {acc[4], acc[5], acc[6], acc[7]};
    float4* po = reinterpret_cast<float4*>(out + (size_t)t * 2048 + c);
    po[0] = o0; po[1] = o1;
}

extern "C" void kernel_launch(void* const* d_in, const int* in_sizes, int n_in,
                              void* d_out, int out_size, void* d_ws, size_t ws_size,
                              hipStream_t stream) {
    const float* x = (const float*)d_in[0];
    const float* gate_w = (const float*)d_in[1];
    const float* wg = (const float*)d_in[2];
    const float* wu = (const float*)d_in[3];
    const float* wd = (const float*)d_in[4];
    const float* swg = (const float*)d_in[5];
    const float* swu = (const float*)d_in[6];
    const float* swd = (const float*)d_in[7];
    float* out = (float*)d_out;

    char* ws = (char*)d_ws;
    size_t off = 0;
    auto alloc = [&](size_t bytes) {
        void* p = ws + off;
        off = (off + bytes + 255) & ~(size_t)255;
        return p;
    };
    u16* xbT = (u16*)alloc((size_t)T_TOK * DIMK * 2);                  // 16.8 MB
    u16* H = (u16*)alloc((size_t)MAXPADROWS * INTERN * 2);             // 59.8 MB
    u16* Hs = (u16*)alloc((size_t)T_TOK * SINTER * 2);                 // 16.8 MB
    u16* Ye = (u16*)alloc((size_t)MAXPADROWS * 2048 * 2);              // 119.6 MB
    u16* Yss = (u16*)alloc((size_t)2 * T_TOK * 2048 * 2);              // 33.6 MB
    int* ids = (int*)alloc((size_t)NEXP * T_TOK * 4);
    int* tok2row = (int*)alloc((size_t)T_TOK * NTOPK * 4);
    float* wtok = (float*)alloc((size_t)T_TOK * NTOPK * 4);
    int* counts = (int*)alloc(NEXP * 4);
    int* poff = (int*)alloc(NEXP * 4);
    u16* WcatS = (u16*)alloc((size_t)(2 * SINTER) * DIMK * 2);         // 16.8 MB
    u16* swdT = (u16*)alloc((size_t)DIMK * SINTER * 2);                // 8.4 MB
    u16* WcatE = (u16*)alloc((size_t)NEXP * (2 * INTERN) * DIMK * 2);  // 268.4 MB
    u16* wdT = WcatE;  // alias: wd transpose runs after GEMM1 consumed WcatE (stream-ordered)

    hipMemsetAsync(counts, 0, NEXP * 4, stream);
    cast_x_tiled_kernel<<<(T_TOK * DIMK) / (256 * 8), 256, 0, stream>>>(x, xbT);
    gate_kernel<<<T_TOK, 64, 0, stream>>>(x, gate_w, counts, ids, tok2row, wtok);
    scan_kernel<<<1, 64, 0, stream>>>(counts, poff);

    // weight reshapes
    cat_trans_kernel<DIMK, SINTER><<<dim3(SINTER / 32, DIMK / 64, 1), 256, 0, stream>>>(swg, swu, WcatS);
    cat_trans_kernel<DIMK, INTERN><<<dim3(INTERN / 32, DIMK / 64, NEXP), 256, 0, stream>>>(wg, wu, WcatE);
    trans_tiled_kernel<SINTER, DIMK><<<dim3(DIMK / 64, SINTER / 64, 1), 256, 0, stream>>>(swd, swdT);

    // fused GEMM1 (m201 8-phase, gather-free expert A from xbT)
    gemm1_fused_kernel<<<dim3(16, 8, 34), 512, 0, stream>>>(
        xbT, WcatE, H, WcatS, Hs, counts, poff, ids);

    // wd transpose into aliased WcatE region (GEMM1 done by stream order)
    trans_tiled_kernel<INTERN, DIMK><<<dim3(DIMK / 64, INTERN / 64, NEXP), 256, 0, stream>>>(wd, wdT);

    // fused GEMM2 (m201 8-phase): expert -> Ye; shared K-split -> Yss
    gemm2_fused_kernel<<<dim3(16, 8, 34), 512, 0, stream>>>(
        H, wdT, Ye, Hs, swdT, Yss, counts, poff);

    // final combine -> out
    combine_kernel<<<T_TOK, 256, 0, stream>>>(Yss, Ye, tok2row, wtok, poff, out);
}

// Round 13
// 1006.202 us; speedup vs baseline: 1.3223x; 1.0279x over previous
//
#include <hip/hip_runtime.h>
#include <hip/hip_bf16.h>

typedef float f32x4 __attribute__((ext_vector_type(4)));
typedef __bf16 bf16x8 __attribute__((ext_vector_type(8)));
typedef unsigned short u16;

#define T_TOK 4096
#define DIMK 2048
#define INTERN 1024
#define NEXP 32
#define NTOPK 6
#define NGRP 8
#define NTOPG 4
#define SINTER 2048
#define MAXPADROWS 29184

__device__ __forceinline__ void glds16(const void* g, void* l) {
    auto* gp = (const __attribute__((address_space(1))) int*)(g);
    auto* lp = (__attribute__((address_space(3))) int*)(l);
    __builtin_amdgcn_global_load_lds(gp, lp, 16, 0, 0);
}

// Chunked+swizzled layout for [Rows][K] bf16: row-chunks 128, k-chunks 64.
// In-chunk (16KB=8192 elems): off = row*64 + ((g ^ (row&7))<<3) + (k&7), g=(k>>3)&7.
__device__ __forceinline__ size_t toff(int row, int k, int K) {
    int g = (k >> 3) & 7;
    return (size_t)(row >> 7) * (size_t)(128 * K) + (size_t)(k >> 6) * 8192 +
           (size_t)((row & 127) * 64 + ((g ^ (row & 7)) << 3) + (k & 7));
}

// ---------------- cast x fp32 -> bf16 chunked ----------------
__global__ __launch_bounds__(256) void cast_x_tiled_kernel(const float* __restrict__ in, u16* __restrict__ out) {
    int gi = (blockIdx.x * 256 + threadIdx.x) * 8;
    int row = gi >> 11, k = gi & 2047;
    const float4* p = reinterpret_cast<const float4*>(in + gi);
    float4 a = p[0], b = p[1];
    bf16x8 v;
    v[0] = (__bf16)a.x; v[1] = (__bf16)a.y; v[2] = (__bf16)a.z; v[3] = (__bf16)a.w;
    v[4] = (__bf16)b.x; v[5] = (__bf16)b.y; v[6] = (__bf16)b.z; v[7] = (__bf16)b.w;
    *reinterpret_cast<bf16x8*>(out + toff(row, k, DIMK)) = v;
}

// ---------------- single transpose: fp32 [KD][JD] -> bf16 chunked [JD][KD] ----------------
template <int KD, int JD>
__global__ __launch_bounds__(256) void trans_tiled_kernel(const float* __restrict__ in, u16* __restrict__ out) {
    __shared__ float tile[64 * 65];
    const int t = threadIdx.x;
    const float* ib = in + (size_t)blockIdx.z * KD * JD;
    u16* ob = out + (size_t)blockIdx.z * KD * JD;
    const int j0 = blockIdx.x * 64, k0 = blockIdx.y * 64;
    {
        const int c4 = (t & 15) * 4;
#pragma unroll
        for (int i = 0; i < 4; ++i) {
            const int r = (t >> 4) + i * 16;
            float4 v = *reinterpret_cast<const float4*>(&ib[(size_t)(k0 + r) * JD + j0 + c4]);
            tile[r * 65 + c4 + 0] = v.x;
            tile[r * 65 + c4 + 1] = v.y;
            tile[r * 65 + c4 + 2] = v.z;
            tile[r * 65 + c4 + 3] = v.w;
        }
    }
    __syncthreads();
    {
        const int jl = t >> 2, kh = (t & 3) * 16;
        const int n = j0 + jl;
        bf16x8 v0, v1;
#pragma unroll
        for (int j = 0; j < 8; ++j) v0[j] = (__bf16)tile[(kh + j) * 65 + jl];
#pragma unroll
        for (int j = 0; j < 8; ++j) v1[j] = (__bf16)tile[(kh + 8 + j) * 65 + jl];
        *reinterpret_cast<bf16x8*>(ob + toff(n, k0 + kh, KD)) = v0;
        *reinterpret_cast<bf16x8*>(ob + toff(n, k0 + kh + 8, KD)) = v1;
    }
}

// ---------------- cat transpose: wg,wu [KD][JD] -> Wcat chunked [2*JD][KD] ----------------
template <int KD, int JD>
__global__ __launch_bounds__(256) void cat_trans_kernel(const float* __restrict__ g0, const float* __restrict__ u0,
                                                        u16* __restrict__ out) {
    __shared__ float tile[64 * 65];
    const int t = threadIdx.x;
    const size_t so = (size_t)blockIdx.z * KD * JD;
    u16* ob = out + (size_t)blockIdx.z * (2 * (size_t)KD * JD);
    const int j0 = blockIdx.x * 32, k0 = blockIdx.y * 64;
    const int kl = t >> 2, jf = (t & 3) * 4;
#pragma unroll
    for (int s = 0; s < 2; ++s) {
        const float* src = (s ? u0 : g0) + so;
#pragma unroll
        for (int rep = 0; rep < 2; ++rep) {
            int jb = jf + rep * 16;
            float4 v = *reinterpret_cast<const float4*>(&src[(size_t)(k0 + kl) * JD + j0 + jb]);
            int nl = ((jb >> 4) << 5) + s * 16 + (jb & 15);
            tile[kl * 65 + nl + 0] = v.x;
            tile[kl * 65 + nl + 1] = v.y;
            tile[kl * 65 + nl + 2] = v.z;
            tile[kl * 65 + nl + 3] = v.w;
        }
    }
    __syncthreads();
    {
        const int nl = t >> 2, kh = (t & 3) * 16;
        const int n = 2 * j0 + nl;
        bf16x8 v0, v1;
#pragma unroll
        for (int j = 0; j < 8; ++j) v0[j] = (__bf16)tile[(kh + j) * 65 + nl];
#pragma unroll
        for (int j = 0; j < 8; ++j) v1[j] = (__bf16)tile[(kh + 8 + j) * 65 + nl];
        *reinterpret_cast<bf16x8*>(ob + toff(n, k0 + kh, KD)) = v0;
        *reinterpret_cast<bf16x8*>(ob + toff(n, k0 + kh + 8, KD)) = v1;
    }
}

// ---------------- gate ----------------
__global__ __launch_bounds__(64) void gate_kernel(const float* __restrict__ x, const float* __restrict__ gw,
                                                  int* __restrict__ counts, int* __restrict__ ids,
                                                  int* __restrict__ tok2row, float* __restrict__ wtok) {
    const int t = blockIdx.x;
    const int lane = threadIdx.x;
    __shared__ float logits[NEXP];
    const float4* xr = reinterpret_cast<const float4*>(x + (size_t)t * DIMK);
    for (int e = 0; e < NEXP; ++e) {
        const float4* gr = reinterpret_cast<const float4*>(gw + (size_t)e * DIMK);
        float acc = 0.f;
#pragma unroll
        for (int i = 0; i < DIMK / 4 / 64; ++i) {
            float4 xv = xr[lane + i * 64];
            float4 gv = gr[lane + i * 64];
            acc += xv.x * gv.x + xv.y * gv.y + xv.z * gv.z + xv.w * gv.w;
        }
#pragma unroll
        for (int s = 32; s; s >>= 1) acc += __shfl_xor(acc, s);
        if (lane == 0) logits[e] = acc;
    }
    if (lane != 0) return;
    float sc[NEXP];
#pragma unroll
    for (int e = 0; e < NEXP; ++e) sc[e] = logits[e];
    float mx = sc[0];
#pragma unroll
    for (int e = 1; e < NEXP; ++e) mx = fmaxf(mx, sc[e]);
    float ssum = 0.f;
#pragma unroll
    for (int e = 0; e < NEXP; ++e) { sc[e] = __expf(sc[e] - mx); ssum += sc[e]; }
    const float inv = 1.f / ssum;
    float gsc[NGRP];
#pragma unroll
    for (int g = 0; g < NGRP; ++g) {
        float m2 = sc[g * 4];
#pragma unroll
        for (int j = 1; j < 4; ++j) m2 = fmaxf(m2, sc[g * 4 + j]);
        gsc[g] = m2;
    }
    int gsel = 0;
    for (int r = 0; r < NTOPG; ++r) {
        float bv = -1.f; int bi = 0;
#pragma unroll
        for (int g = 0; g < NGRP; ++g) {
            bool c = (((gsel >> g) & 1) == 0) && (gsc[g] > bv);
            bv = c ? gsc[g] : bv; bi = c ? g : bi;
        }
        gsel |= (1 << bi);
    }
    float msk[NEXP];
#pragma unroll
    for (int e = 0; e < NEXP; ++e) msk[e] = ((gsel >> (e >> 2)) & 1) ? sc[e] : -1.f;
    for (int r = 0; r < NTOPK; ++r) {
        float bv = -3.f; int bi = 0;
#pragma unroll
        for (int e = 0; e < NEXP; ++e) {
            bool c = msk[e] > bv;
            bv = c ? msk[e] : bv; bi = c ? e : bi;
        }
#pragma unroll
        for (int e = 0; e < NEXP; ++e) if (e == bi) msk[e] = -2.f;
        float w = bv * inv;
        int slot = atomicAdd(&counts[bi], 1);
        ids[bi * T_TOK + slot] = t;
        tok2row[t * NTOPK + r] = (bi << 12) | slot;
        wtok[t * NTOPK + r] = w;
    }
}

__global__ void scan_kernel(const int* __restrict__ counts, int* __restrict__ poff) {
    if (threadIdx.x == 0) {
        int o = 0;
        for (int e = 0; e < NEXP; ++e) { poff[e] = o; o += (counts[e] + 127) & ~127; }
    }
}

// ================= 256x256 / BK=64 / 8-wave (2M x 4N) / asymmetric-depth 8-phase core =================
// A: 2-buf, staged t+1 at ph0 (L3-warm source). B: 3-buf, staged t+2 at ph1/ph2 (cold HBM, 8-phase flight).
// Per K-tile t (abuf=t&1, bbuf=t%3):
//  ph0: dsrA(m0)+dsrB0; SA(t+1,h0)+SA(t+1,h1) -> abuf^1; bar; 16 MFMA m0n0; bar
//  ph1: dsrB1;          SB(t+2,h0) -> (t+2)%3;           bar; 16 MFMA m0n1; bar
//  ph2: dsrA(m1);       SB(t+2,h1) -> (t+2)%3;           bar; 16 MFMA m1n1; bar
//  ph3:                 16 MFMA m1n0; vmcnt(4|0); bar
// vmcnt(4) leaves only SB(t+2)'s 4 loads in flight => A(t+1),B(t+1) landed.

// GEMM1 fused: expert (z<32, gather-A from xbT via ids) + shared (z>=32).
__global__ __launch_bounds__(512, 2) void gemm1_fused_kernel(
    const u16* __restrict__ xbT, const u16* __restrict__ WcatE, u16* __restrict__ H,
    const u16* __restrict__ WcatS, u16* __restrict__ Hs,
    const int* __restrict__ counts, const int* __restrict__ poff, const int* __restrict__ ids) {
    __shared__ u16 Alds[2 * 16384];
    __shared__ u16 Blds[3 * 16384];
    constexpr int NT = DIMK / 64;  // 32

    int bm, bn, M, Mpad, hbase, HKdim, e = 0;
    const u16* b0;
    u16* ho;
    bool gath;
    if (blockIdx.z < 32) {
        int lin = blockIdx.x + 16 * (blockIdx.y + 8 * blockIdx.z);
        e = 31 - (((lin >> 10) << 3) | (lin & 7));
        int j = (lin >> 3) & 127;
        bm = j & 15; bn = j >> 4;
        M = counts[e];
        if (bm * 256 >= M) return;
        Mpad = (M + 127) & ~127;
        hbase = poff[e];
        b0 = WcatE + (size_t)e * 2048 * DIMK;
        ho = H; HKdim = INTERN; gath = true;
    } else {
        int lin = blockIdx.x + 16 * (blockIdx.y + 8 * (blockIdx.z - 32));
        int swz = (lin & 7) * 32 + (lin >> 3);
        bm = swz & 15; bn = swz >> 4;
        M = T_TOK; Mpad = T_TOK; hbase = 0;
        b0 = WcatS; ho = Hs; HKdim = SINTER; gath = false;
    }

    const int tid = threadIdx.x;
    const int t8 = tid * 8;
    size_t aSrc[2][2];
#pragma unroll
    for (int h = 0; h < 2; ++h)
#pragma unroll
        for (int j = 0; j < 2; ++j) {
            int drow = j * 64 + (tid >> 3);
            int row = bm * 256 + h * 128 + drow;
            int tok;
            if (gath) { int cr = row < M ? row : M - 1; tok = ids[e * T_TOK + cr]; }
            else tok = row;
            int slot = (tid & 7) ^ (drow & 7) ^ (tok & 7);
            aSrc[h][j] = (size_t)(tok >> 7) * (size_t)(128 * 2048) + (size_t)((tok & 127) * 64 + slot * 8);
        }
    const u16* bCh[2] = { b0 + (size_t)(2 * bn + 0) * (128 * 2048), b0 + (size_t)(2 * bn + 1) * (128 * 2048) };

    const int lane = tid & 63, wv = tid >> 6;
    const int wr = wv >> 2, wc = wv & 3;
    const int l15 = lane & 15, lk = lane >> 4;

    f32x4 acc[8][4];
#pragma unroll
    for (int m = 0; m < 8; ++m)
#pragma unroll
        for (int n = 0; n < 4; ++n) acc[m][n] = {0.f, 0.f, 0.f, 0.f};

    auto SA = [&](int kt, int h, int buf) {
        glds16(xbT + aSrc[h][0] + (size_t)kt * 8192, &Alds[buf * 16384 + h * 8192 + t8]);
        glds16(xbT + aSrc[h][1] + (size_t)kt * 8192, &Alds[buf * 16384 + h * 8192 + 4096 + t8]);
    };
    auto SB = [&](int kt, int h, int buf) {
        glds16(bCh[h] + (size_t)kt * 8192 + t8, &Blds[buf * 16384 + h * 8192 + t8]);
        glds16(bCh[h] + (size_t)kt * 8192 + 4096 + t8, &Blds[buf * 16384 + h * 8192 + 4096 + t8]);
    };
    bf16x8 afr[4][2], bfr0[2][2], bfr1[2][2];
    auto DSRA = [&](int buf, int mh) {
#pragma unroll
        for (int mi = 0; mi < 4; ++mi)
#pragma unroll
            for (int ki = 0; ki < 2; ++ki) {
                int rl = wr * 128 + mh * 64 + mi * 16 + l15;
                int g = ki * 4 + lk;
                afr[mi][ki] = *reinterpret_cast<const bf16x8*>(
                    &Alds[buf * 16384 + (rl >> 7) * 8192 + (rl & 127) * 64 + ((g ^ (rl & 7)) << 3)]);
            }
    };
    auto DSRB = [&](int buf, int nh, bf16x8 (&bf)[2][2]) {
#pragma unroll
        for (int nj = 0; nj < 2; ++nj)
#pragma unroll
            for (int ki = 0; ki < 2; ++ki) {
                int rc = wc * 64 + (nh * 2 + nj) * 16 + l15;
                int g = ki * 4 + lk;
                bf[nj][ki] = *reinterpret_cast<const bf16x8*>(
                    &Blds[buf * 16384 + (rc >> 7) * 8192 + (rc & 127) * 64 + ((g ^ (rc & 7)) << 3)]);
            }
    };

    // prologue: A(0)->abuf0 (4), B(0)->bbuf0 (4), B(1)->bbuf1 (4). vmcnt(4) leaves B(1) in flight.
    SA(0, 0, 0); SA(0, 1, 0);
    SB(0, 0, 0); SB(0, 1, 0);
    SB(1, 0, 1); SB(1, 1, 1);
    asm volatile("s_waitcnt vmcnt(4)" ::: "memory");
    __builtin_amdgcn_s_barrier();

#pragma unroll 1
    for (int t = 0; t < NT; ++t) {
        const int abuf = t & 1;
        const int bbuf = t % 3;
        const int b3 = (t + 2) % 3;
        // ph0: m0 x n0 ; stage A(t+1) both halves
        DSRA(abuf, 0);
        DSRB(bbuf, 0, bfr0);
        if (t + 1 < NT) { SA(t + 1, 0, abuf ^ 1); SA(t + 1, 1, abuf ^ 1); }
        __builtin_amdgcn_s_barrier();
        __builtin_amdgcn_s_setprio(1);
#pragma unroll
        for (int ki = 0; ki < 2; ++ki)
#pragma unroll
            for (int mi = 0; mi < 4; ++mi)
#pragma unroll
                for (int nj = 0; nj < 2; ++nj)
                    acc[mi][nj] = __builtin_amdgcn_mfma_f32_16x16x32_bf16(afr[mi][ki], bfr0[nj][ki], acc[mi][nj], 0, 0, 0);
        __builtin_amdgcn_s_setprio(0);
        __builtin_amdgcn_s_barrier();
        // ph1: m0 x n1 ; stage B(t+2) half0
        DSRB(bbuf, 1, bfr1);
        if (t + 2 < NT) SB(t + 2, 0, b3);
        __builtin_amdgcn_s_barrier();
        __builtin_amdgcn_s_setprio(1);
#pragma unroll
        for (int ki = 0; ki < 2; ++ki)
#pragma unroll
            for (int mi = 0; mi < 4; ++mi)
#pragma unroll
                for (int nj = 0; nj < 2; ++nj)
                    acc[mi][2 + nj] = __builtin_amdgcn_mfma_f32_16x16x32_bf16(afr[mi][ki], bfr1[nj][ki], acc[mi][2 + nj], 0, 0, 0);
        __builtin_amdgcn_s_setprio(0);
        __builtin_amdgcn_s_barrier();
        // ph2: m1 x n1 ; stage B(t+2) half1
        DSRA(abuf, 1);
        if (t + 2 < NT) SB(t + 2, 1, b3);
        __builtin_amdgcn_s_barrier();
        __builtin_amdgcn_s_setprio(1);
#pragma unroll
        for (int ki = 0; ki < 2; ++ki)
#pragma unroll
            for (int mi = 0; mi < 4; ++mi)
#pragma unroll
                for (int nj = 0; nj < 2; ++nj)
                    acc[4 + mi][2 + nj] = __builtin_amdgcn_mfma_f32_16x16x32_bf16(afr[mi][ki], bfr1[nj][ki], acc[4 + mi][2 + nj], 0, 0, 0);
        __builtin_amdgcn_s_setprio(0);
        __builtin_amdgcn_s_barrier();
        // ph3: m1 x n0 (bfr0 retained; no staging)
        __builtin_amdgcn_s_setprio(1);
#pragma unroll
        for (int ki = 0; ki < 2; ++ki)
#pragma unroll
            for (int mi = 0; mi < 4; ++mi)
#pragma unroll
                for (int nj = 0; nj < 2; ++nj)
                    acc[4 + mi][nj] = __builtin_amdgcn_mfma_f32_16x16x32_bf16(afr[mi][ki], bfr0[nj][ki], acc[4 + mi][nj], 0, 0, 0);
        __builtin_amdgcn_s_setprio(0);
        if (t + 2 < NT) { asm volatile("s_waitcnt vmcnt(4)" ::: "memory"); }
        else { asm volatile("s_waitcnt vmcnt(0)" ::: "memory"); }
        __builtin_amdgcn_s_barrier();
    }

    // epilogue: h = silu(g)*u -> H chunked
#pragma unroll
    for (int mI = 0; mI < 8; ++mI) {
#pragma unroll
        for (int r = 0; r < 4; ++r) {
            int grow = bm * 256 + wr * 128 + mI * 16 + lk * 4 + r;
            if (grow < Mpad) {
#pragma unroll
                for (int nh = 0; nh < 2; ++nh) {
                    float gg = acc[mI][nh * 2 + 0][r];
                    float uu = acc[mI][nh * 2 + 1][r];
                    float h = gg / (1.f + __expf(-gg)) * uu;
                    int n = bn * 256 + wc * 64 + nh * 32 + l15;
                    int jcol = ((n >> 5) << 4) + (n & 15);
                    __bf16 hb = (__bf16)h;
                    ho[toff(hbase + grow, jcol, HKdim)] = __builtin_bit_cast(u16, hb);
                }
            }
        }
    }
}

// GEMM2 fused: expert (z<32) -> Ye rows; shared (z>=32) K-split -> Yss slices.
__global__ __launch_bounds__(512, 2) void gemm2_fused_kernel(
    const u16* __restrict__ H, const u16* __restrict__ wdT, u16* __restrict__ Ye,
    const u16* __restrict__ Hs, const u16* __restrict__ swdT, u16* __restrict__ Yss,
    const int* __restrict__ counts, const int* __restrict__ poff) {
    __shared__ u16 Alds[2 * 16384];
    __shared__ u16 Blds[3 * 16384];
    constexpr int NT = 16;

    int bm, bn, M, rowbase, AKK, kt0;
    const u16 *aBase, *bBase;
    u16* yo;
    if (blockIdx.z < 32) {
        int lin = blockIdx.x + 16 * (blockIdx.y + 8 * blockIdx.z);
        int e = 31 - (((lin >> 10) << 3) | (lin & 7));
        int j = (lin >> 3) & 127;
        bm = j & 15; bn = j >> 4;
        M = counts[e];
        if (bm * 256 >= M) return;
        rowbase = poff[e];
        aBase = H + (size_t)poff[e] * INTERN;
        bBase = wdT + (size_t)e * 2048 * INTERN;
        yo = Ye; AKK = INTERN; kt0 = 0;
    } else {
        int lin = blockIdx.x + 16 * (blockIdx.y + 8 * (blockIdx.z - 32));
        int swz = (lin & 7) * 32 + (lin >> 3);
        bm = swz & 15; bn = (swz >> 4) & 7;
        int ks = swz >> 7;
        M = T_TOK; rowbase = ks * T_TOK;
        aBase = Hs; bBase = swdT; yo = Yss; AKK = SINTER; kt0 = ks * 16;
    }
    const u16* aCh[2] = { aBase + (size_t)(2 * bm + 0) * (size_t)(128 * AKK) + (size_t)kt0 * 8192,
                          aBase + (size_t)(2 * bm + 1) * (size_t)(128 * AKK) + (size_t)kt0 * 8192 };
    const u16* bCh[2] = { bBase + (size_t)(2 * bn + 0) * (size_t)(128 * AKK) + (size_t)kt0 * 8192,
                          bBase + (size_t)(2 * bn + 1) * (size_t)(128 * AKK) + (size_t)kt0 * 8192 };
    const int tid = threadIdx.x;
    const int t8 = tid * 8;
    const int lane = tid & 63, wv = tid >> 6;
    const int wr = wv >> 2, wc = wv & 3;
    const int l15 = lane & 15, lk = lane >> 4;

    f32x4 acc[8][4];
#pragma unroll
    for (int m = 0; m < 8; ++m)
#pragma unroll
        for (int n = 0; n < 4; ++n) acc[m][n] = {0.f, 0.f, 0.f, 0.f};

    auto SA = [&](int kt, int h, int buf) {
        glds16(aCh[h] + (size_t)kt * 8192 + t8, &Alds[buf * 16384 + h * 8192 + t8]);
        glds16(aCh[h] + (size_t)kt * 8192 + 4096 + t8, &Alds[buf * 16384 + h * 8192 + 4096 + t8]);
    };
    auto SB = [&](int kt, int h, int buf) {
        glds16(bCh[h] + (size_t)kt * 8192 + t8, &Blds[buf * 16384 + h * 8192 + t8]);
        glds16(bCh[h] + (size_t)kt * 8192 + 4096 + t8, &Blds[buf * 16384 + h * 8192 + 4096 + t8]);
    };
    bf16x8 afr[4][2], bfr0[2][2], bfr1[2][2];
    auto DSRA = [&](int buf, int mh) {
#pragma unroll
        for (int mi = 0; mi < 4; ++mi)
#pragma unroll
            for (int ki = 0; ki < 2; ++ki) {
                int rl = wr * 128 + mh * 64 + mi * 16 + l15;
                int g = ki * 4 + lk;
                afr[mi][ki] = *reinterpret_cast<const bf16x8*>(
                    &Alds[buf * 16384 + (rl >> 7) * 8192 + (rl & 127) * 64 + ((g ^ (rl & 7)) << 3)]);
            }
    };
    auto DSRB = [&](int buf, int nh, bf16x8 (&bf)[2][2]) {
#pragma unroll
        for (int nj = 0; nj < 2; ++nj)
#pragma unroll
            for (int ki = 0; ki < 2; ++ki) {
                int rc = wc * 64 + (nh * 2 + nj) * 16 + l15;
                int g = ki * 4 + lk;
                bf[nj][ki] = *reinterpret_cast<const bf16x8*>(
                    &Blds[buf * 16384 + (rc >> 7) * 8192 + (rc & 127) * 64 + ((g ^ (rc & 7)) << 3)]);
            }
    };

    SA(0, 0, 0); SA(0, 1, 0);
    SB(0, 0, 0); SB(0, 1, 0);
    SB(1, 0, 1); SB(1, 1, 1);
    asm volatile("s_waitcnt vmcnt(4)" ::: "memory");
    __builtin_amdgcn_s_barrier();

#pragma unroll 1
    for (int t = 0; t < NT; ++t) {
        const int abuf = t & 1;
        const int bbuf = t % 3;
        const int b3 = (t + 2) % 3;
        DSRA(abuf, 0);
        DSRB(bbuf, 0, bfr0);
        if (t + 1 < NT) { SA(t + 1, 0, abuf ^ 1); SA(t + 1, 1, abuf ^ 1); }
        __builtin_amdgcn_s_barrier();
        __builtin_amdgcn_s_setprio(1);
#pragma unroll
        for (int ki = 0; ki < 2; ++ki)
#pragma unroll
            for (int mi = 0; mi < 4; ++mi)
#pragma unroll
                for (int nj = 0; nj < 2; ++nj)
                    acc[mi][nj] = __builtin_amdgcn_mfma_f32_16x16x32_bf16(afr[mi][ki], bfr0[nj][ki], acc[mi][nj], 0, 0, 0);
        __builtin_amdgcn_s_setprio(0);
        __builtin_amdgcn_s_barrier();
        DSRB(bbuf, 1, bfr1);
        if (t + 2 < NT) SB(t + 2, 0, b3);
        __builtin_amdgcn_s_barrier();
        __builtin_amdgcn_s_setprio(1);
#pragma unroll
        for (int ki = 0; ki < 2; ++ki)
#pragma unroll
            for (int mi = 0; mi < 4; ++mi)
#pragma unroll
                for (int nj = 0; nj < 2; ++nj)
                    acc[mi][2 + nj] = __builtin_amdgcn_mfma_f32_16x16x32_bf16(afr[mi][ki], bfr1[nj][ki], acc[mi][2 + nj], 0, 0, 0);
        __builtin_amdgcn_s_setprio(0);
        __builtin_amdgcn_s_barrier();
        DSRA(abuf, 1);
        if (t + 2 < NT) SB(t + 2, 1, b3);
        __builtin_amdgcn_s_barrier();
        __builtin_amdgcn_s_setprio(1);
#pragma unroll
        for (int ki = 0; ki < 2; ++ki)
#pragma unroll
            for (int mi = 0; mi < 4; ++mi)
#pragma unroll
                for (int nj = 0; nj < 2; ++nj)
                    acc[4 + mi][2 + nj] = __builtin_amdgcn_mfma_f32_16x16x32_bf16(afr[mi][ki], bfr1[nj][ki], acc[4 + mi][2 + nj], 0, 0, 0);
        __builtin_amdgcn_s_setprio(0);
        __builtin_amdgcn_s_barrier();
        __builtin_amdgcn_s_setprio(1);
#pragma unroll
        for (int ki = 0; ki < 2; ++ki)
#pragma unroll
            for (int mi = 0; mi < 4; ++mi)
#pragma unroll
                for (int nj = 0; nj < 2; ++nj)
                    acc[4 + mi][nj] = __builtin_amdgcn_mfma_f32_16x16x32_bf16(afr[mi][ki], bfr0[nj][ki], acc[4 + mi][nj], 0, 0, 0);
        __builtin_amdgcn_s_setprio(0);
        if (t + 2 < NT) { asm volatile("s_waitcnt vmcnt(4)" ::: "memory"); }
        else { asm volatile("s_waitcnt vmcnt(0)" ::: "memory"); }
        __builtin_amdgcn_s_barrier();
    }

#pragma unroll
    for (int mI = 0; mI < 8; ++mI) {
#pragma unroll
        for (int r = 0; r < 4; ++r) {
            int grow = bm * 256 + wr * 128 + mI * 16 + lk * 4 + r;
            if (grow < M) {
                u16* yr = yo + (size_t)(rowbase + grow) * 2048;
#pragma unroll
                for (int ni = 0; ni < 4; ++ni) {
                    int col = bn * 256 + wc * 64 + ni * 16 + l15;
                    __bf16 yb = (__bf16)acc[mI][ni][r];
                    yr[col] = __builtin_bit_cast(u16, yb);
                }
            }
        }
    }
}

// ---------------- combine: out[t] = Yss0[t] + Yss1[t] + sum_r w_r * Ye[row_r] ----------------
__global__ __launch_bounds__(256) void combine_kernel(const u16* __restrict__ Yss, const u16* __restrict__ Ye,
                                                      const int* __restrict__ tok2row, const float* __restrict__ wtok,
                                                      const int* __restrict__ poff, float* __restrict__ out) {
    const int t = blockIdx.x;
    const int c = threadIdx.x * 8;
    bf16x8 v0 = *reinterpret_cast<const bf16x8*>(Yss + (size_t)t * 2048 + c);
    bf16x8 v1 = *reinterpret_cast<const bf16x8*>(Yss + (size_t)(T_TOK + t) * 2048 + c);
    float acc[8];
#pragma unroll
    for (int j = 0; j < 8; ++j) acc[j] = (float)v0[j] + (float)v1[j];
#pragma unroll
    for (int r = 0; r < NTOPK; ++r) {
        int pk = tok2row[t * NTOPK + r];
        int e = pk >> 12, sl = pk & 4095;
        int row = poff[e] + sl;
        float w = wtok[t * NTOPK + r];
        bf16x8 v = *reinterpret_cast<const bf16x8*>(Ye + (size_t)row * 2048 + c);
#pragma unroll
        for (int j = 0; j < 8; ++j) acc[j] += w * (float)v[j];
    }
    float4 o0 = {acc[0], acc[1], acc[2], acc[3]};
    float4 o1 = {acc[4], acc[5], acc[6], acc[7]};
    float4* po = reinterpret_cast<float4*>(out + (size_t)t * 2048 + c);
    po[0] = o0; po[1] = o1;
}

extern "C" void kernel_launch(void* const* d_in, const int* in_sizes, int n_in,
                              void* d_out, int out_size, void* d_ws, size_t ws_size,
                              hipStream_t stream) {
    const float* x = (const float*)d_in[0];
    const float* gate_w = (const float*)d_in[1];
    const float* wg = (const float*)d_in[2];
    const float* wu = (const float*)d_in[3];
    const float* wd = (const float*)d_in[4];
    const float* swg = (const float*)d_in[5];
    const float* swu = (const float*)d_in[6];
    const float* swd = (const float*)d_in[7];
    float* out = (float*)d_out;

    char* ws = (char*)d_ws;
    size_t off = 0;
    auto alloc = [&](size_t bytes) {
        void* p = ws + off;
        off = (off + bytes + 255) & ~(size_t)255;
        return p;
    };
    u16* xbT = (u16*)alloc((size_t)T_TOK * DIMK * 2);                  // 16.8 MB
    u16* H = (u16*)alloc((size_t)MAXPADROWS * INTERN * 2);             // 59.8 MB
    u16* Hs = (u16*)alloc((size_t)T_TOK * SINTER * 2);                 // 16.8 MB
    u16* Ye = (u16*)alloc((size_t)MAXPADROWS * 2048 * 2);              // 119.6 MB
    u16* Yss = (u16*)alloc((size_t)2 * T_TOK * 2048 * 2);              // 33.6 MB
    int* ids = (int*)alloc((size_t)NEXP * T_TOK * 4);
    int* tok2row = (int*)alloc((size_t)T_TOK * NTOPK * 4);
    float* wtok = (float*)alloc((size_t)T_TOK * NTOPK * 4);
    int* counts = (int*)alloc(NEXP * 4);
    int* poff = (int*)alloc(NEXP * 4);
    u16* WcatS = (u16*)alloc((size_t)(2 * SINTER) * DIMK * 2);         // 16.8 MB
    u16* swdT = (u16*)alloc((size_t)DIMK * SINTER * 2);                // 8.4 MB
    u16* WcatE = (u16*)alloc((size_t)NEXP * (2 * INTERN) * DIMK * 2);  // 268.4 MB
    u16* wdT = WcatE;  // alias: wd transpose runs after GEMM1 consumed WcatE (stream-ordered)

    hipMemsetAsync(counts, 0, NEXP * 4, stream);
    cast_x_tiled_kernel<<<(T_TOK * DIMK) / (256 * 8), 256, 0, stream>>>(x, xbT);
    gate_kernel<<<T_TOK, 64, 0, stream>>>(x, gate_w, counts, ids, tok2row, wtok);
    scan_kernel<<<1, 64, 0, stream>>>(counts, poff);

    // weight reshapes
    cat_trans_kernel<DIMK, SINTER><<<dim3(SINTER / 32, DIMK / 64, 1), 256, 0, stream>>>(swg, swu, WcatS);
    cat_trans_kernel<DIMK, INTERN><<<dim3(INTERN / 32, DIMK / 64, NEXP), 256, 0, stream>>>(wg, wu, WcatE);
    trans_tiled_kernel<SINTER, DIMK><<<dim3(DIMK / 64, SINTER / 64, 1), 256, 0, stream>>>(swd, swdT);

    // fused GEMM1 (asymmetric-depth 8-phase, gather-free expert A from xbT)
    gemm1_fused_kernel<<<dim3(16, 8, 34), 512, 0, stream>>>(
        xbT, WcatE, H, WcatS, Hs, counts, poff, ids);

    // wd transpose into aliased WcatE region (GEMM1 done by stream order)
    trans_tiled_kernel<INTERN, DIMK><<<dim3(DIMK / 64, INTERN / 64, NEXP), 256, 0, stream>>>(wd, wdT);

    // fused GEMM2 (asymmetric-depth 8-phase): expert -> Ye; shared K-split -> Yss
    gemm2_fused_kernel<<<dim3(16, 8, 34), 512, 0, stream>>>(
        H, wdT, Ye, Hs, swdT, Yss, counts, poff);

    // final combine -> out
    combine_kernel<<<T_TOK, 256, 0, stream>>>(Yss, Ye, tok2row, wtok, poff, out);
}